// Round 14
// baseline (276.347 us; speedup 1.0000x reference)
//
#include <hip/hip_runtime.h>
#include <hip/hip_bf16.h>
#include <math.h>

// Restormer-style channel attention. Round 14: kg -> kg128, occupancy fix.
// Block 64m x 128px, 4 waves of 64m x 32px (acc[4][2]=32 AGPR), no A-LDS
// (A-frags direct from L2 split planes), B-LDS 20.5KB, lb(256,4) ->
// 16 waves/CU (was 12). Register audit ~111 < 128 cap. All other kernels
// frozen from R13 (203us best).
// B=4, C=192, H=W=128, HEADS=4, ch=48, HW=16384.

#define B_ 4
#define C_ 192
#define H_ 128
#define W_ 128
#define HW_ 16384
#define HEADS_ 4
#define CH_ 48
#define CHUNKS_ 64

typedef __attribute__((ext_vector_type(8))) __bf16 bf16x8;
typedef __attribute__((ext_vector_type(8))) unsigned short u16x8;
typedef __attribute__((ext_vector_type(4))) float f32x4;

__device__ __forceinline__ unsigned short rne_bf16(float f) {
    unsigned int u = __float_as_uint(f);
    u += 0x7FFFu + ((u >> 16) & 1u);
    return (unsigned short)(u >> 16);
}
__device__ __forceinline__ float bf16_f32(unsigned short h) {
    return __uint_as_float(((unsigned int)h) << 16);
}

// split weights into bf16 hi/lo (RNE both)
__global__ void k0_split(const float* __restrict__ wq,
                         unsigned short* __restrict__ wH,
                         unsigned short* __restrict__ wL, int n) {
    int idx = blockIdx.x * 256 + threadIdx.x;
    if (idx < n) {
        float f = wq[idx];
        unsigned short h = rne_bf16(f);
        wH[idx] = h;
        wL[idx] = rne_bf16(f - bf16_f32(h));
    }
}

// ---- GEMM: Y[b][m][p] = sum_k A[m][k]*X[b][k][p] ----
// Block 64m x 128px, 4 waves (each 64m x 32px). B staged in LDS split hi/lo
// (stride-40 u16 rows); A frags direct from L2-resident split planes.
__global__ __launch_bounds__(256, 4) void kg128(
    const unsigned short* __restrict__ Ah, const unsigned short* __restrict__ Al,
    int aStrideB, const float* __restrict__ X, float* __restrict__ Y) {
    __shared__ unsigned short BhL[128 * 40];
    __shared__ unsigned short BlL[128 * 40];
    int t = threadIdx.x;
    int wave = t >> 6, lane = t & 63;
    int lm = lane & 15, kg = lane >> 4;
    int p0 = blockIdx.x * 128;
    int m0 = blockIdx.y * 64;
    int b = blockIdx.z;
    const unsigned short* Abh = Ah + (size_t)b * aStrideB + (size_t)m0 * C_;
    const unsigned short* Abl = Al + (size_t)b * aStrideB + (size_t)m0 * C_;
    int px_s = t & 127, kh_s = t >> 7;   // staging: pixel col, 16-k half
    const float* Xs = X + (size_t)b * C_ * HW_ + p0 + px_s;

    f32x4 acc[4][2];
#pragma unroll
    for (int mi = 0; mi < 4; ++mi)
#pragma unroll
        for (int ni = 0; ni < 2; ++ni) acc[mi][ni] = (f32x4)(0.f);

    for (int s = 0; s < 6; ++s) {
        int k0 = s * 32;
        __syncthreads();
        // stage B tile [128 px][32 k]: this thread covers 16 k's of one px
        {
            const float* xp = Xs + (size_t)(k0 + kh_s * 16) * HW_;
            float xv[16];
#pragma unroll
            for (int i = 0; i < 16; ++i) xv[i] = xp[(size_t)i * HW_];
#pragma unroll
            for (int c8 = 0; c8 < 2; ++c8) {
                u16x8 hh, ll;
#pragma unroll
                for (int j = 0; j < 8; ++j) {
                    float f = xv[c8 * 8 + j];
                    unsigned int u = __float_as_uint(f);
                    hh[j] = (unsigned short)(u >> 16);  // trunc hi
                    float r = f - __uint_as_float(u & 0xFFFF0000u);
                    ll[j] = rne_bf16(r);
                }
                *(u16x8*)&BhL[px_s * 40 + kh_s * 16 + c8 * 8] = hh;
                *(u16x8*)&BlL[px_s * 40 + kh_s * 16 + c8 * 8] = ll;
            }
        }
        // A fragments direct from global/L2
        bf16x8 fah[4], fal[4];
#pragma unroll
        for (int mi = 0; mi < 4; ++mi) {
            size_t ao = (size_t)(lm + 16 * mi) * C_ + k0 + kg * 8;
            fah[mi] = __builtin_bit_cast(bf16x8, *(const u16x8*)&Abh[ao]);
            fal[mi] = __builtin_bit_cast(bf16x8, *(const u16x8*)&Abl[ao]);
        }
        __syncthreads();
        bf16x8 fbh[2], fbl[2];
#pragma unroll
        for (int ni = 0; ni < 2; ++ni) {
            int ro = (wave * 32 + ni * 16 + lm) * 40 + kg * 8;
            fbh[ni] = __builtin_bit_cast(bf16x8, *(const u16x8*)&BhL[ro]);
            fbl[ni] = __builtin_bit_cast(bf16x8, *(const u16x8*)&BlL[ro]);
        }
#pragma unroll
        for (int mi = 0; mi < 4; ++mi)
#pragma unroll
            for (int ni = 0; ni < 2; ++ni) {
                acc[mi][ni] = __builtin_amdgcn_mfma_f32_16x16x32_bf16(
                    fah[mi], fbh[ni], acc[mi][ni], 0, 0, 0);
                acc[mi][ni] = __builtin_amdgcn_mfma_f32_16x16x32_bf16(
                    fah[mi], fbl[ni], acc[mi][ni], 0, 0, 0);
                acc[mi][ni] = __builtin_amdgcn_mfma_f32_16x16x32_bf16(
                    fal[mi], fbh[ni], acc[mi][ni], 0, 0, 0);
            }
    }
    // epilogue: D col = lane&15 (px), row = 4*kg + r (m)
#pragma unroll
    for (int mi = 0; mi < 4; ++mi)
#pragma unroll
        for (int ni = 0; ni < 2; ++ni) {
            int oc = m0 + mi * 16 + kg * 4;
            int px = p0 + wave * 32 + ni * 16 + lm;
            float* yp = Y + ((size_t)b * C_ + oc) * HW_ + px;
#pragma unroll
            for (int r = 0; r < 4; ++r) yp[(size_t)r * HW_] = acc[mi][ni][r];
        }
}

// packed-split-input variant (X = u32: lo16=hi-bf16, hi16=lo-bf16)
__global__ __launch_bounds__(256, 4) void kg128_p(
    const unsigned short* __restrict__ Ah, const unsigned short* __restrict__ Al,
    int aStrideB, const unsigned int* __restrict__ X, float* __restrict__ Y) {
    __shared__ unsigned short BhL[128 * 40];
    __shared__ unsigned short BlL[128 * 40];
    int t = threadIdx.x;
    int wave = t >> 6, lane = t & 63;
    int lm = lane & 15, kg = lane >> 4;
    int p0 = blockIdx.x * 128;
    int m0 = blockIdx.y * 64;
    int b = blockIdx.z;
    const unsigned short* Abh = Ah + (size_t)b * aStrideB + (size_t)m0 * C_;
    const unsigned short* Abl = Al + (size_t)b * aStrideB + (size_t)m0 * C_;
    int px_s = t & 127, kh_s = t >> 7;
    const unsigned int* Xs = X + (size_t)b * C_ * HW_ + p0 + px_s;

    f32x4 acc[4][2];
#pragma unroll
    for (int mi = 0; mi < 4; ++mi)
#pragma unroll
        for (int ni = 0; ni < 2; ++ni) acc[mi][ni] = (f32x4)(0.f);

    for (int s = 0; s < 6; ++s) {
        int k0 = s * 32;
        __syncthreads();
        {
            const unsigned int* xp = Xs + (size_t)(k0 + kh_s * 16) * HW_;
            unsigned int xv[16];
#pragma unroll
            for (int i = 0; i < 16; ++i) xv[i] = xp[(size_t)i * HW_];
#pragma unroll
            for (int c8 = 0; c8 < 2; ++c8) {
                u16x8 hh, ll;
#pragma unroll
                for (int j = 0; j < 8; ++j) {
                    unsigned int u = xv[c8 * 8 + j];
                    hh[j] = (unsigned short)(u & 0xFFFFu);
                    ll[j] = (unsigned short)(u >> 16);
                }
                *(u16x8*)&BhL[px_s * 40 + kh_s * 16 + c8 * 8] = hh;
                *(u16x8*)&BlL[px_s * 40 + kh_s * 16 + c8 * 8] = ll;
            }
        }
        bf16x8 fah[4], fal[4];
#pragma unroll
        for (int mi = 0; mi < 4; ++mi) {
            size_t ao = (size_t)(lm + 16 * mi) * C_ + k0 + kg * 8;
            fah[mi] = __builtin_bit_cast(bf16x8, *(const u16x8*)&Abh[ao]);
            fal[mi] = __builtin_bit_cast(bf16x8, *(const u16x8*)&Abl[ao]);
        }
        __syncthreads();
        bf16x8 fbh[2], fbl[2];
#pragma unroll
        for (int ni = 0; ni < 2; ++ni) {
            int ro = (wave * 32 + ni * 16 + lm) * 40 + kg * 8;
            fbh[ni] = __builtin_bit_cast(bf16x8, *(const u16x8*)&BhL[ro]);
            fbl[ni] = __builtin_bit_cast(bf16x8, *(const u16x8*)&BlL[ro]);
        }
#pragma unroll
        for (int mi = 0; mi < 4; ++mi)
#pragma unroll
            for (int ni = 0; ni < 2; ++ni) {
                acc[mi][ni] = __builtin_amdgcn_mfma_f32_16x16x32_bf16(
                    fah[mi], fbh[ni], acc[mi][ni], 0, 0, 0);
                acc[mi][ni] = __builtin_amdgcn_mfma_f32_16x16x32_bf16(
                    fah[mi], fbl[ni], acc[mi][ni], 0, 0, 0);
                acc[mi][ni] = __builtin_amdgcn_mfma_f32_16x16x32_bf16(
                    fal[mi], fbh[ni], acc[mi][ni], 0, 0, 0);
            }
    }
#pragma unroll
    for (int mi = 0; mi < 4; ++mi)
#pragma unroll
        for (int ni = 0; ni < 2; ++ni) {
            int oc = m0 + mi * 16 + kg * 4;
            int px = p0 + wave * 32 + ni * 16 + lm;
            float* yp = Y + ((size_t)b * C_ + oc) * HW_ + px;
#pragma unroll
            for (int r = 0; r < 4; ++r) yp[(size_t)r * HW_] = acc[mi][ni][r];
        }
}

// depthwise 3x3, zero pad; 4x4 register tile per thread. Emits packed
// split-bf16 (u32: lo16=trunc-hi, hi16=rne-lo). If ssP != nullptr, also emits
// deterministic per-block sum-of-squares partial: ssP[(b*C+c)*4 + rowblk].
__global__ __launch_bounds__(256, 6) void k2_dwconv(
    const float* __restrict__ y1, const float* __restrict__ wdw,
    unsigned int* __restrict__ dstP, float* __restrict__ ssP, int g) {
    __shared__ float wss[4];
    int t = threadIdx.x;
    int c = blockIdx.y, b = blockIdx.z;
    int cg = (t & 31) * 4;
    int r0i = blockIdx.x * 32 + (t >> 5) * 4;
    const float* yp = y1 + ((size_t)b * C_ + c) * HW_;
    const float* wd = wdw + (size_t)(g * C_ + c) * 9;
    float w0 = wd[0], w1 = wd[1], w2 = wd[2];
    float w3 = wd[3], w4 = wd[4], w5 = wd[5];
    float w6 = wd[6], w7 = wd[7], w8 = wd[8];
    bool lv = cg > 0, rv = cg < W_ - 4;

    float4 mid[6];
    float lf[6], rt[6];
#pragma unroll
    for (int i = 0; i < 6; ++i) {
        int rr = r0i - 1 + i;
        if (rr >= 0 && rr < H_) {
            const float* rowp = yp + (size_t)rr * W_;
            mid[i] = *(const float4*)&rowp[cg];
            lf[i] = lv ? rowp[cg - 1] : 0.f;
            rt[i] = rv ? rowp[cg + 4] : 0.f;
        } else {
            mid[i] = make_float4(0.f, 0.f, 0.f, 0.f);
            lf[i] = 0.f;
            rt[i] = 0.f;
        }
    }
    float ss = 0.f;
#pragma unroll
    for (int i = 0; i < 4; ++i) {
        float o0 = 0.f, o1 = 0.f, o2 = 0.f, o3 = 0.f;
#pragma unroll
        for (int k = 0; k < 3; ++k) {
            float4 m = mid[i + k];
            float L = lf[i + k], R = rt[i + k];
            float wa = (k == 0) ? w0 : (k == 1) ? w3 : w6;
            float wb = (k == 0) ? w1 : (k == 1) ? w4 : w7;
            float wc = (k == 0) ? w2 : (k == 1) ? w5 : w8;
            o0 = fmaf(wa, L,   fmaf(wb, m.x, fmaf(wc, m.y, o0)));
            o1 = fmaf(wa, m.x, fmaf(wb, m.y, fmaf(wc, m.z, o1)));
            o2 = fmaf(wa, m.y, fmaf(wb, m.z, fmaf(wc, m.w, o2)));
            o3 = fmaf(wa, m.z, fmaf(wb, m.w, fmaf(wc, R,   o3)));
        }
        ss += o0 * o0 + o1 * o1 + o2 * o2 + o3 * o3;
        size_t oi = ((size_t)b * C_ + c) * HW_ + (size_t)(r0i + i) * W_ + cg;
        uint4 pk;
        float vals[4] = {o0, o1, o2, o3};
        unsigned int pks[4];
#pragma unroll
        for (int j = 0; j < 4; ++j) {
            unsigned int u = __float_as_uint(vals[j]);
            unsigned short h = (unsigned short)(u >> 16);
            float r = vals[j] - __uint_as_float(u & 0xFFFF0000u);
            pks[j] = (unsigned int)h | ((unsigned int)rne_bf16(r) << 16);
        }
        pk.x = pks[0]; pk.y = pks[1]; pk.z = pks[2]; pk.w = pks[3];
        *(uint4*)&dstP[oi] = pk;
    }
    if (ssP != nullptr) {
#pragma unroll
        for (int m = 32; m >= 1; m >>= 1) ss += __shfl_xor(ss, m, 64);
        if ((t & 63) == 0) wss[t >> 6] = ss;
        __syncthreads();
        if (t == 0)
            ssP[((size_t)b * C_ + c) * 4 + blockIdx.x] =
                (wss[0] + wss[1]) + (wss[2] + wss[3]);
    }
}

// S-GEMM partials via split-bf16 MFMA. Per (b,h,chunk of 256 px):
// Sp[bh][chunk][cq*48+ck]
__global__ __launch_bounds__(256, 3) void k3_qk(
    const unsigned int* __restrict__ qp, const unsigned int* __restrict__ kp,
    float* __restrict__ Sp) {
    __shared__ unsigned int smem[12672];
    unsigned short* qh = (unsigned short*)smem;   // [48][132] u16
    unsigned short* ql = qh + 6336;
    unsigned short* kh = qh + 12672;
    unsigned short* kl = qh + 19008;
    float* red = (float*)smem;                    // alias for reduce
    int t = threadIdx.x;
    int w = t >> 6, lane = t & 63, lm = lane & 15, kg = lane >> 4;
    int chunk = blockIdx.x, h = blockIdx.y, b = blockIdx.z;
    const unsigned int* qb = qp + ((size_t)b * C_ + h * CH_) * HW_;
    const unsigned int* kb = kp + ((size_t)b * C_ + h * CH_) * HW_;

    f32x4 acc[3][3];
#pragma unroll
    for (int mi = 0; mi < 3; ++mi)
#pragma unroll
        for (int ni = 0; ni < 3; ++ni) acc[mi][ni] = (f32x4)(0.f);

    for (int s = 0; s < 2; ++s) {
        int base = chunk * 256 + s * 128;
        __syncthreads();
#pragma unroll
        for (int i = 0; i < 12; ++i) {
            int p = t + i * 256;
            int c = p >> 6, jp = p & 63;
            uint2 qv = *(const uint2*)&qb[(size_t)c * HW_ + base + jp * 2];
            uint2 kv = *(const uint2*)&kb[(size_t)c * HW_ + base + jp * 2];
            int da = c * 66 + jp;
            ((unsigned int*)qh)[da] = (qv.x & 0xFFFFu) | (qv.y << 16);
            ((unsigned int*)ql)[da] = (qv.x >> 16) | (qv.y & 0xFFFF0000u);
            ((unsigned int*)kh)[da] = (kv.x & 0xFFFFu) | (kv.y << 16);
            ((unsigned int*)kl)[da] = (kv.x >> 16) | (kv.y & 0xFFFF0000u);
        }
        __syncthreads();
        bf16x8 fqh[3], fql[3], fkh[3], fkl[3];
#pragma unroll
        for (int mi = 0; mi < 3; ++mi) {
            int off = (lm + 16 * mi) * 132 + w * 32 + kg * 8;
            fqh[mi] = __builtin_bit_cast(bf16x8, *(const u16x8*)&qh[off]);
            fql[mi] = __builtin_bit_cast(bf16x8, *(const u16x8*)&ql[off]);
            fkh[mi] = __builtin_bit_cast(bf16x8, *(const u16x8*)&kh[off]);
            fkl[mi] = __builtin_bit_cast(bf16x8, *(const u16x8*)&kl[off]);
        }
#pragma unroll
        for (int mi = 0; mi < 3; ++mi)
#pragma unroll
            for (int ni = 0; ni < 3; ++ni) {
                acc[mi][ni] = __builtin_amdgcn_mfma_f32_16x16x32_bf16(
                    fqh[mi], fkh[ni], acc[mi][ni], 0, 0, 0);
                acc[mi][ni] = __builtin_amdgcn_mfma_f32_16x16x32_bf16(
                    fqh[mi], fkl[ni], acc[mi][ni], 0, 0, 0);
                acc[mi][ni] = __builtin_amdgcn_mfma_f32_16x16x32_bf16(
                    fql[mi], fkh[ni], acc[mi][ni], 0, 0, 0);
            }
    }
    __syncthreads();
#pragma unroll
    for (int mi = 0; mi < 3; ++mi)
#pragma unroll
        for (int ni = 0; ni < 3; ++ni) {
            int tile = mi * 3 + ni;
            *(f32x4*)&red[w * 2304 + tile * 256 + lane * 4] = acc[mi][ni];
        }
    __syncthreads();
    size_t ob = ((size_t)(b * HEADS_ + h) * CHUNKS_ + chunk) * 2304;
    for (int idx = t; idx < 2304; idx += 256) {
        float sv = (red[idx] + red[2304 + idx]) +
                   (red[4608 + idx] + red[6912 + idx]);
        int tile = idx >> 8, li = idx & 255;
        int ln = li >> 2, r = li & 3;
        int mi = tile / 3, ni = tile - mi * 3;
        int sidx = (mi * 16 + (ln >> 4) * 4 + r) * 48 + ni * 16 + (ln & 15);
        Sp[ob + sidx] = sv;
    }
}

// per-(bh, q-row c): reduce 64 chunk partials, scale by norms+temp, softmax
// over 48 k-channels via wave shuffles (fixed trees, deterministic), write
// P[bh][d*48 + c] (transposed for k4c).
__global__ __launch_bounds__(256, 4) void k4r_softmax(
    const float* __restrict__ Sp, const float* __restrict__ ssPq,
    const float* __restrict__ ssPk, const float* __restrict__ temp,
    float* __restrict__ P) {
    __shared__ float red[4][64];
    int t = threadIdx.x;
    int w = t >> 6, d = t & 63;
    int c = blockIdx.x, bh = blockIdx.y;
    int b = bh >> 2, h = bh & 3;
    float s = 0.f;
    if (d < 48) {
        const float* sp = Sp + (size_t)bh * CHUNKS_ * 2304 + c * 48 + d;
#pragma unroll
        for (int j = 0; j < 16; ++j)
            s += sp[(size_t)(w * 16 + j) * 2304];
    }
    red[w][d] = s;
    __syncthreads();
    if (w == 0) {
        float tot = (red[0][d] + red[1][d]) + (red[2][d] + red[3][d]);
        const float* spq = ssPq + ((size_t)b * C_ + h * CH_ + c) * 4;
        float rq = 1.f / fmaxf(
            sqrtf(fmaxf((spq[0] + spq[1]) + (spq[2] + spq[3]), 0.f)), 1e-12f);
        float logit = -1e30f;
        if (d < 48) {
            const float* spk = ssPk + ((size_t)b * C_ + h * CH_ + d) * 4;
            float rk = 1.f / fmaxf(
                sqrtf(fmaxf((spk[0] + spk[1]) + (spk[2] + spk[3]), 0.f)), 1e-12f);
            logit = tot * (rq * temp[h]) * rk;
        }
        float m = logit;
#pragma unroll
        for (int mm = 1; mm < 64; mm <<= 1) m = fmaxf(m, __shfl_xor(m, mm, 64));
        float e = (d < 48) ? expf(logit - m) : 0.f;
        float sum = e;
#pragma unroll
        for (int mm = 1; mm < 64; mm <<= 1) sum += __shfl_xor(sum, mm, 64);
        if (d < 48)
            P[(size_t)bh * 2304 + d * 48 + c] = e * (1.f / sum);
    }
}

// MT fold: MT[b][o][h*48+d] = sum_c wp[o][h*48+c] * P[b,h][d][c], split-bf16.
// Grid (12 o-tiles of 16, 4 b). P staged with stride-49 rows (conflict-free).
__global__ __launch_bounds__(256, 2) void k4c_fold(
    const float* __restrict__ P, const float* __restrict__ wp,
    unsigned short* __restrict__ MTh, unsigned short* __restrict__ MTl) {
    __shared__ float sP[4 * 48 * 49];   // [h][d][c] stride 49
    __shared__ float wpL[16 * 192];     // [o_local][cg]
    int t = threadIdx.x;
    int o0 = blockIdx.x * 16, b = blockIdx.y;
    const float* Pb = P + (size_t)b * 4 * 2304;
    for (int i = t; i < 4 * 2304; i += 256) {
        int h = i / 2304, rem = i - h * 2304;
        int d = rem / 48, cc = rem - d * 48;
        sP[h * 2352 + d * 49 + cc] = Pb[i];
    }
    for (int i = t; i < 16 * 192; i += 256) {
        int o = i / 192, cc = i - o * 192;
        wpL[i] = wp[(size_t)(o0 + o) * C_ + cc];
    }
    __syncthreads();
    for (int i = t; i < 16 * 192; i += 256) {
        int o = i / 192, cg = i - o * 192;
        int h = cg / 48, d = cg - h * 48;
        const float* wrow = &wpL[o * 192 + h * 48];   // broadcast per (o,h)
        const float* prow = &sP[h * 2352 + d * 49];   // stride-49, spread banks
        float sum = 0.f;
#pragma unroll
        for (int c = 0; c < 48; ++c) sum = fmaf(wrow[c], prow[c], sum);
        size_t oi = ((size_t)b * C_ + o0 + o) * C_ + cg;  // coalesced u16
        unsigned short hh = rne_bf16(sum);
        MTh[oi] = hh;
        MTl[oi] = rne_bf16(sum - bf16_f32(hh));
    }
}

extern "C" void kernel_launch(void* const* d_in, const int* in_sizes, int n_in,
                              void* d_out, int out_size, void* d_ws, size_t ws_size,
                              hipStream_t stream) {
    const float* x     = (const float*)d_in[0];
    const float* wqkv  = (const float*)d_in[1];
    const float* wdw   = (const float*)d_in[2];
    const float* wproj = (const float*)d_in[3];
    const float* temp  = (const float*)d_in[4];
    float* out = (float*)d_out;
    char* ws = (char*)d_ws;

    unsigned short* wqkvH = (unsigned short*)(ws + 0);          // 221184 B
    unsigned short* wqkvL = (unsigned short*)(ws + 221184);     // 221184 B
    unsigned short* MTh   = (unsigned short*)(ws + 442368);     // 294912 B
    unsigned short* MTl   = (unsigned short*)(ws + 737280);     // 294912 B
    float* P    = (float*)(ws + 1032192);                       // 147456 B
    float* ssPq = (float*)(ws + 1179648);                       // 12288 B
    float* ssPk = (float*)(ws + 1191936);                       // 12288 B
    float* y1 = (float*)(ws + 1204224);                         // 50331648 B
    float* Sp = y1;                                             // aliases y1
    unsigned int* q = (unsigned int*)(ws + 51535872);           // 50331648 B
    unsigned int* k = (unsigned int*)(ws + 101867520);          // 50331648 B
    unsigned int* v = q;                                        // v reuses q slab

    hipLaunchKernelGGL(k0_split, dim3(432), dim3(256), 0, stream,
                       wqkv, wqkvH, wqkvL, 576 * 192);
    // q
    hipLaunchKernelGGL(kg128, dim3(128, 3, 4), dim3(256), 0, stream,
                       wqkvH, wqkvL, 0, x, y1);
    hipLaunchKernelGGL(k2_dwconv, dim3(4, 192, 4), dim3(256), 0, stream,
                       y1, wdw, q, ssPq, 0);
    // k
    hipLaunchKernelGGL(kg128, dim3(128, 3, 4), dim3(256), 0, stream,
                       wqkvH + 192 * 192, wqkvL + 192 * 192, 0, x, y1);
    hipLaunchKernelGGL(k2_dwconv, dim3(4, 192, 4), dim3(256), 0, stream,
                       y1, wdw, k, ssPk, 1);
    // attention -> P -> MT (split)
    hipLaunchKernelGGL(k3_qk, dim3(CHUNKS_, 4, 4), dim3(256), 0, stream, q, k, Sp);
    hipLaunchKernelGGL(k4r_softmax, dim3(48, 16), dim3(256), 0, stream,
                       Sp, ssPq, ssPk, temp, P);
    hipLaunchKernelGGL(k4c_fold, dim3(12, 4), dim3(256), 0, stream,
                       P, wproj, MTh, MTl);
    // v (packed, into q slab)
    hipLaunchKernelGGL(kg128, dim3(128, 3, 4), dim3(256), 0, stream,
                       wqkvH + 2 * 192 * 192, wqkvL + 2 * 192 * 192, 0, x, y1);
    hipLaunchKernelGGL(k2_dwconv, dim3(4, 192, 4), dim3(256), 0, stream,
                       y1, wdw, v, (float*)nullptr, 2);
    // out = M @ v
    hipLaunchKernelGGL(kg128_p, dim3(128, 3, 4), dim3(256), 0, stream,
                       MTh, MTl, C_ * C_, v, out);
}

// Round 15
// 204.788 us; speedup vs baseline: 1.3494x; 1.3494x over previous
//
#include <hip/hip_runtime.h>
#include <hip/hip_bf16.h>
#include <math.h>

// Restormer-style channel attention. Round 15: plain RNE-bf16 GEMMs
// (drop the hi/lo split; error budget 3.73e-3 vs predicted ~1-2e-3).
// q/k/v slabs become u16 bf16 (half the traffic); kg LDS 25.6KB ->
// lb(256,4) with full 256px tile; k3 18 MFMA (was 54).
// Fallback if absmax fails: R13 split config (203us).
// B=4, C=192, H=W=128, HEADS=4, ch=48, HW=16384.

#define B_ 4
#define C_ 192
#define H_ 128
#define W_ 128
#define HW_ 16384
#define HEADS_ 4
#define CH_ 48
#define CHUNKS_ 64

typedef __attribute__((ext_vector_type(8))) __bf16 bf16x8;
typedef __attribute__((ext_vector_type(8))) unsigned short u16x8;
typedef __attribute__((ext_vector_type(4))) float f32x4;

__device__ __forceinline__ unsigned short rne_bf16(float f) {
    unsigned int u = __float_as_uint(f);
    u += 0x7FFFu + ((u >> 16) & 1u);
    return (unsigned short)(u >> 16);
}
__device__ __forceinline__ float bf16_f32(unsigned short h) {
    return __uint_as_float(((unsigned int)h) << 16);
}

// weights -> bf16 (RNE)
__global__ void k0_bf16(const float* __restrict__ wq,
                        unsigned short* __restrict__ wB, int n) {
    int idx = blockIdx.x * 256 + threadIdx.x;
    if (idx < n) wB[idx] = rne_bf16(wq[idx]);
}

// ---- GEMM: Y[b][m][p] = sum_k A_bf16[m][k] * rne(X[b][k][p]) ----
// Block 64m x 256px, 4 waves (each 64m x 64px). A+B staged in LDS as bf16
// (stride-40 u16 rows, conflict-free b128 reads). lb(256,4).
__global__ __launch_bounds__(256, 4) void kg_f32(
    const unsigned short* __restrict__ A, int aStrideB,
    const float* __restrict__ X, float* __restrict__ Y) {
    __shared__ unsigned short AhL[64 * 40];
    __shared__ unsigned short BhL[256 * 40];
    int t = threadIdx.x;
    int wave = t >> 6, lane = t & 63;
    int lm = lane & 15, kg = lane >> 4;
    int p0 = blockIdx.x * 256;
    int m0 = blockIdx.y * 64;
    int b = blockIdx.z;
    const unsigned short* Ab = A + (size_t)b * aStrideB;
    const float* Xb = X + (size_t)b * C_ * HW_ + p0 + t;
    int ar = t >> 2, ac = (t & 3) * 8;

    f32x4 acc[4][4];
#pragma unroll
    for (int mi = 0; mi < 4; ++mi)
#pragma unroll
        for (int ni = 0; ni < 4; ++ni) acc[mi][ni] = (f32x4)(0.f);

    for (int s = 0; s < 6; ++s) {
        int k0 = s * 32;
        __syncthreads();
        *(u16x8*)&AhL[ar * 40 + ac] =
            *(const u16x8*)&Ab[(size_t)(m0 + ar) * C_ + k0 + ac];
#pragma unroll
        for (int half = 0; half < 2; ++half) {
            const float* xp = Xb + (size_t)(k0 + half * 16) * HW_;
            float xv[16];
#pragma unroll
            for (int i = 0; i < 16; ++i) xv[i] = xp[(size_t)i * HW_];
#pragma unroll
            for (int c8 = 0; c8 < 2; ++c8) {
                u16x8 hh;
#pragma unroll
                for (int j = 0; j < 8; ++j) hh[j] = rne_bf16(xv[c8 * 8 + j]);
                *(u16x8*)&BhL[t * 40 + half * 16 + c8 * 8] = hh;
            }
        }
        __syncthreads();
        bf16x8 fah[4], fbh[4];
#pragma unroll
        for (int mi = 0; mi < 4; ++mi) {
            int ro = (lm + mi * 16) * 40 + kg * 8;
            fah[mi] = __builtin_bit_cast(bf16x8, *(const u16x8*)&AhL[ro]);
        }
#pragma unroll
        for (int ni = 0; ni < 4; ++ni) {
            int ro = (wave * 64 + ni * 16 + lm) * 40 + kg * 8;
            fbh[ni] = __builtin_bit_cast(bf16x8, *(const u16x8*)&BhL[ro]);
        }
#pragma unroll
        for (int mi = 0; mi < 4; ++mi)
#pragma unroll
            for (int ni = 0; ni < 4; ++ni)
                acc[mi][ni] = __builtin_amdgcn_mfma_f32_16x16x32_bf16(
                    fah[mi], fbh[ni], acc[mi][ni], 0, 0, 0);
    }
#pragma unroll
    for (int mi = 0; mi < 4; ++mi)
#pragma unroll
        for (int ni = 0; ni < 4; ++ni) {
            int oc = m0 + mi * 16 + kg * 4;
            int px = p0 + wave * 64 + ni * 16 + lm;
            float* yp = Y + ((size_t)b * C_ + oc) * HW_ + px;
#pragma unroll
            for (int r = 0; r < 4; ++r) yp[(size_t)r * HW_] = acc[mi][ni][r];
        }
}

// bf16-input variant: X is u16 bf16 (the v slab)
__global__ __launch_bounds__(256, 4) void kg_b16(
    const unsigned short* __restrict__ A, int aStrideB,
    const unsigned short* __restrict__ X, float* __restrict__ Y) {
    __shared__ unsigned short AhL[64 * 40];
    __shared__ unsigned short BhL[256 * 40];
    int t = threadIdx.x;
    int wave = t >> 6, lane = t & 63;
    int lm = lane & 15, kg = lane >> 4;
    int p0 = blockIdx.x * 256;
    int m0 = blockIdx.y * 64;
    int b = blockIdx.z;
    const unsigned short* Ab = A + (size_t)b * aStrideB;
    const unsigned short* Xb = X + (size_t)b * C_ * HW_ + p0 + t;
    int ar = t >> 2, ac = (t & 3) * 8;

    f32x4 acc[4][4];
#pragma unroll
    for (int mi = 0; mi < 4; ++mi)
#pragma unroll
        for (int ni = 0; ni < 4; ++ni) acc[mi][ni] = (f32x4)(0.f);

    for (int s = 0; s < 6; ++s) {
        int k0 = s * 32;
        __syncthreads();
        *(u16x8*)&AhL[ar * 40 + ac] =
            *(const u16x8*)&Ab[(size_t)(m0 + ar) * C_ + k0 + ac];
#pragma unroll
        for (int half = 0; half < 2; ++half) {
            const unsigned short* xp = Xb + (size_t)(k0 + half * 16) * HW_;
            unsigned short xv[16];
#pragma unroll
            for (int i = 0; i < 16; ++i) xv[i] = xp[(size_t)i * HW_];
#pragma unroll
            for (int c8 = 0; c8 < 2; ++c8) {
                u16x8 hh;
#pragma unroll
                for (int j = 0; j < 8; ++j) hh[j] = xv[c8 * 8 + j];
                *(u16x8*)&BhL[t * 40 + half * 16 + c8 * 8] = hh;
            }
        }
        __syncthreads();
        bf16x8 fah[4], fbh[4];
#pragma unroll
        for (int mi = 0; mi < 4; ++mi) {
            int ro = (lm + mi * 16) * 40 + kg * 8;
            fah[mi] = __builtin_bit_cast(bf16x8, *(const u16x8*)&AhL[ro]);
        }
#pragma unroll
        for (int ni = 0; ni < 4; ++ni) {
            int ro = (wave * 64 + ni * 16 + lm) * 40 + kg * 8;
            fbh[ni] = __builtin_bit_cast(bf16x8, *(const u16x8*)&BhL[ro]);
        }
#pragma unroll
        for (int mi = 0; mi < 4; ++mi)
#pragma unroll
            for (int ni = 0; ni < 4; ++ni)
                acc[mi][ni] = __builtin_amdgcn_mfma_f32_16x16x32_bf16(
                    fah[mi], fbh[ni], acc[mi][ni], 0, 0, 0);
    }
#pragma unroll
    for (int mi = 0; mi < 4; ++mi)
#pragma unroll
        for (int ni = 0; ni < 4; ++ni) {
            int oc = m0 + mi * 16 + kg * 4;
            int px = p0 + wave * 64 + ni * 16 + lm;
            float* yp = Y + ((size_t)b * C_ + oc) * HW_ + px;
#pragma unroll
            for (int r = 0; r < 4; ++r) yp[(size_t)r * HW_] = acc[mi][ni][r];
        }
}

// depthwise 3x3, zero pad; 4x4 register tile. Emits bf16 (RNE) u16.
// If ssP != nullptr, per-block sum-of-squares of the ROUNDED values.
__global__ __launch_bounds__(256, 6) void k2_dwconv(
    const float* __restrict__ y1, const float* __restrict__ wdw,
    unsigned short* __restrict__ dst, float* __restrict__ ssP, int g) {
    __shared__ float wss[4];
    int t = threadIdx.x;
    int c = blockIdx.y, b = blockIdx.z;
    int cg = (t & 31) * 4;
    int r0i = blockIdx.x * 32 + (t >> 5) * 4;
    const float* yp = y1 + ((size_t)b * C_ + c) * HW_;
    const float* wd = wdw + (size_t)(g * C_ + c) * 9;
    float w0 = wd[0], w1 = wd[1], w2 = wd[2];
    float w3 = wd[3], w4 = wd[4], w5 = wd[5];
    float w6 = wd[6], w7 = wd[7], w8 = wd[8];
    bool lv = cg > 0, rv = cg < W_ - 4;

    float4 mid[6];
    float lf[6], rt[6];
#pragma unroll
    for (int i = 0; i < 6; ++i) {
        int rr = r0i - 1 + i;
        if (rr >= 0 && rr < H_) {
            const float* rowp = yp + (size_t)rr * W_;
            mid[i] = *(const float4*)&rowp[cg];
            lf[i] = lv ? rowp[cg - 1] : 0.f;
            rt[i] = rv ? rowp[cg + 4] : 0.f;
        } else {
            mid[i] = make_float4(0.f, 0.f, 0.f, 0.f);
            lf[i] = 0.f;
            rt[i] = 0.f;
        }
    }
    float ss = 0.f;
#pragma unroll
    for (int i = 0; i < 4; ++i) {
        float o0 = 0.f, o1 = 0.f, o2 = 0.f, o3 = 0.f;
#pragma unroll
        for (int k = 0; k < 3; ++k) {
            float4 m = mid[i + k];
            float L = lf[i + k], R = rt[i + k];
            float wa = (k == 0) ? w0 : (k == 1) ? w3 : w6;
            float wb = (k == 0) ? w1 : (k == 1) ? w4 : w7;
            float wc = (k == 0) ? w2 : (k == 1) ? w5 : w8;
            o0 = fmaf(wa, L,   fmaf(wb, m.x, fmaf(wc, m.y, o0)));
            o1 = fmaf(wa, m.x, fmaf(wb, m.y, fmaf(wc, m.z, o1)));
            o2 = fmaf(wa, m.y, fmaf(wb, m.z, fmaf(wc, m.w, o2)));
            o3 = fmaf(wa, m.z, fmaf(wb, m.w, fmaf(wc, R,   o3)));
        }
        unsigned short h0 = rne_bf16(o0), h1 = rne_bf16(o1);
        unsigned short h2 = rne_bf16(o2), h3 = rne_bf16(o3);
        float f0 = bf16_f32(h0), f1 = bf16_f32(h1);
        float f2 = bf16_f32(h2), f3 = bf16_f32(h3);
        ss += f0 * f0 + f1 * f1 + f2 * f2 + f3 * f3;
        size_t oi = ((size_t)b * C_ + c) * HW_ + (size_t)(r0i + i) * W_ + cg;
        ushort4 pk;
        pk.x = h0; pk.y = h1; pk.z = h2; pk.w = h3;
        *(ushort4*)&dst[oi] = pk;
    }
    if (ssP != nullptr) {
#pragma unroll
        for (int m = 32; m >= 1; m >>= 1) ss += __shfl_xor(ss, m, 64);
        if ((t & 63) == 0) wss[t >> 6] = ss;
        __syncthreads();
        if (t == 0)
            ssP[((size_t)b * C_ + c) * 4 + blockIdx.x] =
                (wss[0] + wss[1]) + (wss[2] + wss[3]);
    }
}

// S-GEMM partials, bf16 inputs. Per (b,h,chunk of 256 px): Sp[bh][chunk][2304]
__global__ __launch_bounds__(256, 4) void k3_qk(
    const unsigned short* __restrict__ qp, const unsigned short* __restrict__ kp,
    float* __restrict__ Sp) {
    __shared__ unsigned int smem[9216];   // 36864 B: staging (25.3KB) / reduce
    unsigned short* qh = (unsigned short*)smem;   // [48][132] u16
    unsigned short* kh = qh + 6336;
    float* red = (float*)smem;                    // 4*2304 floats (alias)
    int t = threadIdx.x;
    int w = t >> 6, lane = t & 63, lm = lane & 15, kg = lane >> 4;
    int chunk = blockIdx.x, h = blockIdx.y, b = blockIdx.z;
    const unsigned int* qb =
        (const unsigned int*)(qp + ((size_t)b * C_ + h * CH_) * HW_);
    const unsigned int* kb =
        (const unsigned int*)(kp + ((size_t)b * C_ + h * CH_) * HW_);

    f32x4 acc[3][3];
#pragma unroll
    for (int mi = 0; mi < 3; ++mi)
#pragma unroll
        for (int ni = 0; ni < 3; ++ni) acc[mi][ni] = (f32x4)(0.f);

    for (int s = 0; s < 2; ++s) {
        int base2 = (chunk * 256 + s * 128) >> 1;   // dword offset in row
        __syncthreads();
#pragma unroll
        for (int i = 0; i < 12; ++i) {
            int p = t + i * 256;          // 0..3071 dwords
            int c = p >> 6, jp = p & 63;  // row, dword-in-row (2 px each)
            int da = c * 66 + jp;
            ((unsigned int*)qh)[da] = qb[(size_t)c * (HW_ / 2) + base2 + jp];
            ((unsigned int*)kh)[da] = kb[(size_t)c * (HW_ / 2) + base2 + jp];
        }
        __syncthreads();
        bf16x8 fqh[3], fkh[3];
#pragma unroll
        for (int mi = 0; mi < 3; ++mi) {
            int off = (lm + 16 * mi) * 132 + w * 32 + kg * 8;
            fqh[mi] = __builtin_bit_cast(bf16x8, *(const u16x8*)&qh[off]);
            fkh[mi] = __builtin_bit_cast(bf16x8, *(const u16x8*)&kh[off]);
        }
#pragma unroll
        for (int mi = 0; mi < 3; ++mi)
#pragma unroll
            for (int ni = 0; ni < 3; ++ni)
                acc[mi][ni] = __builtin_amdgcn_mfma_f32_16x16x32_bf16(
                    fqh[mi], fkh[ni], acc[mi][ni], 0, 0, 0);
    }
    __syncthreads();
#pragma unroll
    for (int mi = 0; mi < 3; ++mi)
#pragma unroll
        for (int ni = 0; ni < 3; ++ni) {
            int tile = mi * 3 + ni;
            *(f32x4*)&red[w * 2304 + tile * 256 + lane * 4] = acc[mi][ni];
        }
    __syncthreads();
    size_t ob = ((size_t)(b * HEADS_ + h) * CHUNKS_ + chunk) * 2304;
    for (int idx = t; idx < 2304; idx += 256) {
        float sv = (red[idx] + red[2304 + idx]) +
                   (red[4608 + idx] + red[6912 + idx]);
        int tile = idx >> 8, li = idx & 255;
        int ln = li >> 2, r = li & 3;
        int mi = tile / 3, ni = tile - mi * 3;
        int sidx = (mi * 16 + (ln >> 4) * 4 + r) * 48 + ni * 16 + (ln & 15);
        Sp[ob + sidx] = sv;
    }
}

// per-(bh, q-row c): reduce chunk partials, norms+temp scale, wave softmax,
// write P[bh][d*48+c]
__global__ __launch_bounds__(256, 4) void k4r_softmax(
    const float* __restrict__ Sp, const float* __restrict__ ssPq,
    const float* __restrict__ ssPk, const float* __restrict__ temp,
    float* __restrict__ P) {
    __shared__ float red[4][64];
    int t = threadIdx.x;
    int w = t >> 6, d = t & 63;
    int c = blockIdx.x, bh = blockIdx.y;
    int b = bh >> 2, h = bh & 3;
    float s = 0.f;
    if (d < 48) {
        const float* sp = Sp + (size_t)bh * CHUNKS_ * 2304 + c * 48 + d;
#pragma unroll
        for (int j = 0; j < 16; ++j)
            s += sp[(size_t)(w * 16 + j) * 2304];
    }
    red[w][d] = s;
    __syncthreads();
    if (w == 0) {
        float tot = (red[0][d] + red[1][d]) + (red[2][d] + red[3][d]);
        const float* spq = ssPq + ((size_t)b * C_ + h * CH_ + c) * 4;
        float rq = 1.f / fmaxf(
            sqrtf(fmaxf((spq[0] + spq[1]) + (spq[2] + spq[3]), 0.f)), 1e-12f);
        float logit = -1e30f;
        if (d < 48) {
            const float* spk = ssPk + ((size_t)b * C_ + h * CH_ + d) * 4;
            float rk = 1.f / fmaxf(
                sqrtf(fmaxf((spk[0] + spk[1]) + (spk[2] + spk[3]), 0.f)), 1e-12f);
            logit = tot * (rq * temp[h]) * rk;
        }
        float m = logit;
#pragma unroll
        for (int mm = 1; mm < 64; mm <<= 1) m = fmaxf(m, __shfl_xor(m, mm, 64));
        float e = (d < 48) ? expf(logit - m) : 0.f;
        float sum = e;
#pragma unroll
        for (int mm = 1; mm < 64; mm <<= 1) sum += __shfl_xor(sum, mm, 64);
        if (d < 48)
            P[(size_t)bh * 2304 + d * 48 + c] = e * (1.f / sum);
    }
}

// MT fold: MT[b][o][h*48+d] = sum_c wp[o][h*48+c] * P[b,h][d][c], bf16 out.
__global__ __launch_bounds__(256, 2) void k4c_fold(
    const float* __restrict__ P, const float* __restrict__ wp,
    unsigned short* __restrict__ MTb) {
    __shared__ float sP[4 * 48 * 49];   // [h][d][c] stride 49
    __shared__ float wpL[16 * 192];     // [o_local][cg]
    int t = threadIdx.x;
    int o0 = blockIdx.x * 16, b = blockIdx.y;
    const float* Pb = P + (size_t)b * 4 * 2304;
    for (int i = t; i < 4 * 2304; i += 256) {
        int h = i / 2304, rem = i - h * 2304;
        int d = rem / 48, cc = rem - d * 48;
        sP[h * 2352 + d * 49 + cc] = Pb[i];
    }
    for (int i = t; i < 16 * 192; i += 256) {
        int o = i / 192, cc = i - o * 192;
        wpL[i] = wp[(size_t)(o0 + o) * C_ + cc];
    }
    __syncthreads();
    for (int i = t; i < 16 * 192; i += 256) {
        int o = i / 192, cg = i - o * 192;
        int h = cg / 48, d = cg - h * 48;
        const float* wrow = &wpL[o * 192 + h * 48];
        const float* prow = &sP[h * 2352 + d * 49];
        float sum = 0.f;
#pragma unroll
        for (int c = 0; c < 48; ++c) sum = fmaf(wrow[c], prow[c], sum);
        MTb[((size_t)b * C_ + o0 + o) * C_ + cg] = rne_bf16(sum);
    }
}

extern "C" void kernel_launch(void* const* d_in, const int* in_sizes, int n_in,
                              void* d_out, int out_size, void* d_ws, size_t ws_size,
                              hipStream_t stream) {
    const float* x     = (const float*)d_in[0];
    const float* wqkv  = (const float*)d_in[1];
    const float* wdw   = (const float*)d_in[2];
    const float* wproj = (const float*)d_in[3];
    const float* temp  = (const float*)d_in[4];
    float* out = (float*)d_out;
    char* ws = (char*)d_ws;

    unsigned short* wqkvB = (unsigned short*)(ws + 0);          // 221184 B
    unsigned short* MTb   = (unsigned short*)(ws + 221184);     // 147456 B
    float* P    = (float*)(ws + 368640);                        // 147456 B
    float* ssPq = (float*)(ws + 516096);                        // 12288 B
    float* ssPk = (float*)(ws + 528384);                        // 12288 B
    float* y1 = (float*)(ws + 540672);                          // 50331648 B
    float* Sp = y1;                                             // aliases y1
    unsigned short* q = (unsigned short*)(ws + 50872320);       // 25165824 B
    unsigned short* k = (unsigned short*)(ws + 76038144);       // 25165824 B
    unsigned short* v = q;                                      // v reuses q slab

    hipLaunchKernelGGL(k0_bf16, dim3(432), dim3(256), 0, stream,
                       wqkv, wqkvB, 576 * 192);
    // q
    hipLaunchKernelGGL(kg_f32, dim3(64, 3, 4), dim3(256), 0, stream,
                       wqkvB, 0, x, y1);
    hipLaunchKernelGGL(k2_dwconv, dim3(4, 192, 4), dim3(256), 0, stream,
                       y1, wdw, q, ssPq, 0);
    // k
    hipLaunchKernelGGL(kg_f32, dim3(64, 3, 4), dim3(256), 0, stream,
                       wqkvB + 192 * 192, 0, x, y1);
    hipLaunchKernelGGL(k2_dwconv, dim3(4, 192, 4), dim3(256), 0, stream,
                       y1, wdw, k, ssPk, 1);
    // attention -> P -> MT (bf16)
    hipLaunchKernelGGL(k3_qk, dim3(CHUNKS_, 4, 4), dim3(256), 0, stream, q, k, Sp);
    hipLaunchKernelGGL(k4r_softmax, dim3(48, 16), dim3(256), 0, stream,
                       Sp, ssPq, ssPk, temp, P);
    hipLaunchKernelGGL(k4c_fold, dim3(12, 4), dim3(256), 0, stream,
                       P, wproj, MTb);
    // v (bf16, into q slab)
    hipLaunchKernelGGL(kg_f32, dim3(64, 3, 4), dim3(256), 0, stream,
                       wqkvB + 2 * 192 * 192, 0, x, y1);
    hipLaunchKernelGGL(k2_dwconv, dim3(4, 192, 4), dim3(256), 0, stream,
                       y1, wdw, v, (float*)nullptr, 2);
    // out = M @ v
    hipLaunchKernelGGL(kg_b16, dim3(64, 3, 4), dim3(256), 0, stream,
                       MTb, C_ * C_, v, out);
}

// Round 16
// 162.779 us; speedup vs baseline: 1.6977x; 1.2581x over previous
//
#include <hip/hip_runtime.h>
#include <hip/hip_bf16.h>
#include <math.h>

// Restormer-style channel attention. Round 16: kg pipelined.
// bf16 single-term GEMM (R15 numerics, absmax 9.77e-4 proven) with
// double-buffered LDS (1 barrier/stage, was 2) + register prefetch of the
// next tile issued BEFORE the MFMA phase (latency hides under compute).
// lb(256,3), LDS 51.2KB -> 3 blocks/CU, peak regs ~150 < 170. All other
// kernels frozen from R15.
// B=4, C=192, H=W=128, HEADS=4, ch=48, HW=16384.

#define B_ 4
#define C_ 192
#define H_ 128
#define W_ 128
#define HW_ 16384
#define HEADS_ 4
#define CH_ 48
#define CHUNKS_ 64

typedef __attribute__((ext_vector_type(8))) __bf16 bf16x8;
typedef __attribute__((ext_vector_type(8))) unsigned short u16x8;
typedef __attribute__((ext_vector_type(4))) float f32x4;

__device__ __forceinline__ unsigned short rne_bf16(float f) {
    unsigned int u = __float_as_uint(f);
    u += 0x7FFFu + ((u >> 16) & 1u);
    return (unsigned short)(u >> 16);
}
__device__ __forceinline__ float bf16_f32(unsigned short h) {
    return __uint_as_float(((unsigned int)h) << 16);
}

// weights -> bf16 (RNE)
__global__ void k0_bf16(const float* __restrict__ wq,
                        unsigned short* __restrict__ wB, int n) {
    int idx = blockIdx.x * 256 + threadIdx.x;
    if (idx < n) wB[idx] = rne_bf16(wq[idx]);
}

// ---- GEMM: Y[b][m][p] = sum_k A_bf16[m][k] * rne(X[b][k][p]) ----
// Block 64m x 256px, 4 waves. Double-buffered LDS, 1 barrier/stage,
// next-tile loads issued before the MFMA phase.
__global__ __launch_bounds__(256, 3) void kg_f32(
    const unsigned short* __restrict__ A, int aStrideB,
    const float* __restrict__ X, float* __restrict__ Y) {
    __shared__ unsigned short AL[2][64 * 40];
    __shared__ unsigned short BL[2][256 * 40];
    int t = threadIdx.x;
    int wave = t >> 6, lane = t & 63;
    int lm = lane & 15, kg = lane >> 4;
    int p0 = blockIdx.x * 256;
    int m0 = blockIdx.y * 64;
    int b = blockIdx.z;
    const unsigned short* Ab = A + (size_t)b * aStrideB + (size_t)m0 * C_;
    const float* Xb = X + (size_t)b * C_ * HW_ + p0 + t;
    int ar = t >> 2, ac = (t & 3) * 8;
    size_t arow = (size_t)ar * C_ + ac;

    f32x4 acc[4][4];
#pragma unroll
    for (int mi = 0; mi < 4; ++mi)
#pragma unroll
        for (int ni = 0; ni < 4; ++ni) acc[mi][ni] = (f32x4)(0.f);

    float xv[32];
    u16x8 av;
    // prologue: stage 0 -> buffers[0]
#pragma unroll
    for (int i = 0; i < 32; ++i) xv[i] = Xb[(size_t)i * HW_];
    av = *(const u16x8*)&Ab[arow];
    *(u16x8*)&AL[0][ar * 40 + ac] = av;
#pragma unroll
    for (int c8 = 0; c8 < 4; ++c8) {
        u16x8 hh;
#pragma unroll
        for (int j = 0; j < 8; ++j) hh[j] = rne_bf16(xv[c8 * 8 + j]);
        *(u16x8*)&BL[0][t * 40 + c8 * 8] = hh;
    }
    __syncthreads();

    for (int s = 0; s < 6; ++s) {
        int cur = s & 1;
        // prefetch next tile into regs (latency hides under frag-read+MFMA)
        if (s < 5) {
            int kn = (s + 1) * 32;
            const float* xp = Xb + (size_t)kn * HW_;
#pragma unroll
            for (int i = 0; i < 32; ++i) xv[i] = xp[(size_t)i * HW_];
            av = *(const u16x8*)&Ab[arow + kn];
        }
        // fragments from LDS[cur]
        bf16x8 fah[4], fbh[4];
#pragma unroll
        for (int mi = 0; mi < 4; ++mi) {
            int ro = (lm + mi * 16) * 40 + kg * 8;
            fah[mi] = __builtin_bit_cast(bf16x8, *(const u16x8*)&AL[cur][ro]);
        }
#pragma unroll
        for (int ni = 0; ni < 4; ++ni) {
            int ro = (wave * 64 + ni * 16 + lm) * 40 + kg * 8;
            fbh[ni] = __builtin_bit_cast(bf16x8, *(const u16x8*)&BL[cur][ro]);
        }
#pragma unroll
        for (int mi = 0; mi < 4; ++mi)
#pragma unroll
            for (int ni = 0; ni < 4; ++ni)
                acc[mi][ni] = __builtin_amdgcn_mfma_f32_16x16x32_bf16(
                    fah[mi], fbh[ni], acc[mi][ni], 0, 0, 0);
        // convert + store next tile into the other buffer
        if (s < 5) {
            int nxt = cur ^ 1;
            *(u16x8*)&AL[nxt][ar * 40 + ac] = av;
#pragma unroll
            for (int c8 = 0; c8 < 4; ++c8) {
                u16x8 hh;
#pragma unroll
                for (int j = 0; j < 8; ++j) hh[j] = rne_bf16(xv[c8 * 8 + j]);
                *(u16x8*)&BL[nxt][t * 40 + c8 * 8] = hh;
            }
        }
        __syncthreads();
    }
#pragma unroll
    for (int mi = 0; mi < 4; ++mi)
#pragma unroll
        for (int ni = 0; ni < 4; ++ni) {
            int oc = m0 + mi * 16 + kg * 4;
            int px = p0 + wave * 64 + ni * 16 + lm;
            float* yp = Y + ((size_t)b * C_ + oc) * HW_ + px;
#pragma unroll
            for (int r = 0; r < 4; ++r) yp[(size_t)r * HW_] = acc[mi][ni][r];
        }
}

// bf16-input variant: X is u16 bf16 (the v slab)
__global__ __launch_bounds__(256, 3) void kg_b16(
    const unsigned short* __restrict__ A, int aStrideB,
    const unsigned short* __restrict__ X, float* __restrict__ Y) {
    __shared__ unsigned short AL[2][64 * 40];
    __shared__ unsigned short BL[2][256 * 40];
    int t = threadIdx.x;
    int wave = t >> 6, lane = t & 63;
    int lm = lane & 15, kg = lane >> 4;
    int p0 = blockIdx.x * 256;
    int m0 = blockIdx.y * 64;
    int b = blockIdx.z;
    const unsigned short* Ab = A + (size_t)b * aStrideB + (size_t)m0 * C_;
    const unsigned short* Xb = X + (size_t)b * C_ * HW_ + p0 + t;
    int ar = t >> 2, ac = (t & 3) * 8;
    size_t arow = (size_t)ar * C_ + ac;

    f32x4 acc[4][4];
#pragma unroll
    for (int mi = 0; mi < 4; ++mi)
#pragma unroll
        for (int ni = 0; ni < 4; ++ni) acc[mi][ni] = (f32x4)(0.f);

    unsigned short xv[32];
    u16x8 av;
#pragma unroll
    for (int i = 0; i < 32; ++i) xv[i] = Xb[(size_t)i * HW_];
    av = *(const u16x8*)&Ab[arow];
    *(u16x8*)&AL[0][ar * 40 + ac] = av;
#pragma unroll
    for (int c8 = 0; c8 < 4; ++c8) {
        u16x8 hh;
#pragma unroll
        for (int j = 0; j < 8; ++j) hh[j] = xv[c8 * 8 + j];
        *(u16x8*)&BL[0][t * 40 + c8 * 8] = hh;
    }
    __syncthreads();

    for (int s = 0; s < 6; ++s) {
        int cur = s & 1;
        if (s < 5) {
            int kn = (s + 1) * 32;
            const unsigned short* xp = Xb + (size_t)kn * HW_;
#pragma unroll
            for (int i = 0; i < 32; ++i) xv[i] = xp[(size_t)i * HW_];
            av = *(const u16x8*)&Ab[arow + kn];
        }
        bf16x8 fah[4], fbh[4];
#pragma unroll
        for (int mi = 0; mi < 4; ++mi) {
            int ro = (lm + mi * 16) * 40 + kg * 8;
            fah[mi] = __builtin_bit_cast(bf16x8, *(const u16x8*)&AL[cur][ro]);
        }
#pragma unroll
        for (int ni = 0; ni < 4; ++ni) {
            int ro = (wave * 64 + ni * 16 + lm) * 40 + kg * 8;
            fbh[ni] = __builtin_bit_cast(bf16x8, *(const u16x8*)&BL[cur][ro]);
        }
#pragma unroll
        for (int mi = 0; mi < 4; ++mi)
#pragma unroll
            for (int ni = 0; ni < 4; ++ni)
                acc[mi][ni] = __builtin_amdgcn_mfma_f32_16x16x32_bf16(
                    fah[mi], fbh[ni], acc[mi][ni], 0, 0, 0);
        if (s < 5) {
            int nxt = cur ^ 1;
            *(u16x8*)&AL[nxt][ar * 40 + ac] = av;
#pragma unroll
            for (int c8 = 0; c8 < 4; ++c8) {
                u16x8 hh;
#pragma unroll
                for (int j = 0; j < 8; ++j) hh[j] = xv[c8 * 8 + j];
                *(u16x8*)&BL[nxt][t * 40 + c8 * 8] = hh;
            }
        }
        __syncthreads();
    }
#pragma unroll
    for (int mi = 0; mi < 4; ++mi)
#pragma unroll
        for (int ni = 0; ni < 4; ++ni) {
            int oc = m0 + mi * 16 + kg * 4;
            int px = p0 + wave * 64 + ni * 16 + lm;
            float* yp = Y + ((size_t)b * C_ + oc) * HW_ + px;
#pragma unroll
            for (int r = 0; r < 4; ++r) yp[(size_t)r * HW_] = acc[mi][ni][r];
        }
}

// depthwise 3x3, zero pad; 4x4 register tile. Emits bf16 (RNE) u16.
// If ssP != nullptr, per-block sum-of-squares of the ROUNDED values.
__global__ __launch_bounds__(256, 6) void k2_dwconv(
    const float* __restrict__ y1, const float* __restrict__ wdw,
    unsigned short* __restrict__ dst, float* __restrict__ ssP, int g) {
    __shared__ float wss[4];
    int t = threadIdx.x;
    int c = blockIdx.y, b = blockIdx.z;
    int cg = (t & 31) * 4;
    int r0i = blockIdx.x * 32 + (t >> 5) * 4;
    const float* yp = y1 + ((size_t)b * C_ + c) * HW_;
    const float* wd = wdw + (size_t)(g * C_ + c) * 9;
    float w0 = wd[0], w1 = wd[1], w2 = wd[2];
    float w3 = wd[3], w4 = wd[4], w5 = wd[5];
    float w6 = wd[6], w7 = wd[7], w8 = wd[8];
    bool lv = cg > 0, rv = cg < W_ - 4;

    float4 mid[6];
    float lf[6], rt[6];
#pragma unroll
    for (int i = 0; i < 6; ++i) {
        int rr = r0i - 1 + i;
        if (rr >= 0 && rr < H_) {
            const float* rowp = yp + (size_t)rr * W_;
            mid[i] = *(const float4*)&rowp[cg];
            lf[i] = lv ? rowp[cg - 1] : 0.f;
            rt[i] = rv ? rowp[cg + 4] : 0.f;
        } else {
            mid[i] = make_float4(0.f, 0.f, 0.f, 0.f);
            lf[i] = 0.f;
            rt[i] = 0.f;
        }
    }
    float ss = 0.f;
#pragma unroll
    for (int i = 0; i < 4; ++i) {
        float o0 = 0.f, o1 = 0.f, o2 = 0.f, o3 = 0.f;
#pragma unroll
        for (int k = 0; k < 3; ++k) {
            float4 m = mid[i + k];
            float L = lf[i + k], R = rt[i + k];
            float wa = (k == 0) ? w0 : (k == 1) ? w3 : w6;
            float wb = (k == 0) ? w1 : (k == 1) ? w4 : w7;
            float wc = (k == 0) ? w2 : (k == 1) ? w5 : w8;
            o0 = fmaf(wa, L,   fmaf(wb, m.x, fmaf(wc, m.y, o0)));
            o1 = fmaf(wa, m.x, fmaf(wb, m.y, fmaf(wc, m.z, o1)));
            o2 = fmaf(wa, m.y, fmaf(wb, m.z, fmaf(wc, m.w, o2)));
            o3 = fmaf(wa, m.z, fmaf(wb, m.w, fmaf(wc, R,   o3)));
        }
        unsigned short h0 = rne_bf16(o0), h1 = rne_bf16(o1);
        unsigned short h2 = rne_bf16(o2), h3 = rne_bf16(o3);
        float f0 = bf16_f32(h0), f1 = bf16_f32(h1);
        float f2 = bf16_f32(h2), f3 = bf16_f32(h3);
        ss += f0 * f0 + f1 * f1 + f2 * f2 + f3 * f3;
        size_t oi = ((size_t)b * C_ + c) * HW_ + (size_t)(r0i + i) * W_ + cg;
        ushort4 pk;
        pk.x = h0; pk.y = h1; pk.z = h2; pk.w = h3;
        *(ushort4*)&dst[oi] = pk;
    }
    if (ssP != nullptr) {
#pragma unroll
        for (int m = 32; m >= 1; m >>= 1) ss += __shfl_xor(ss, m, 64);
        if ((t & 63) == 0) wss[t >> 6] = ss;
        __syncthreads();
        if (t == 0)
            ssP[((size_t)b * C_ + c) * 4 + blockIdx.x] =
                (wss[0] + wss[1]) + (wss[2] + wss[3]);
    }
}

// S-GEMM partials, bf16 inputs. Per (b,h,chunk of 256 px): Sp[bh][chunk][2304]
__global__ __launch_bounds__(256, 4) void k3_qk(
    const unsigned short* __restrict__ qp, const unsigned short* __restrict__ kp,
    float* __restrict__ Sp) {
    __shared__ unsigned int smem[9216];   // 36864 B: staging / reduce alias
    unsigned short* qh = (unsigned short*)smem;   // [48][132] u16
    unsigned short* kh = qh + 6336;
    float* red = (float*)smem;                    // 4*2304 floats (alias)
    int t = threadIdx.x;
    int w = t >> 6, lane = t & 63, lm = lane & 15, kg = lane >> 4;
    int chunk = blockIdx.x, h = blockIdx.y, b = blockIdx.z;
    const unsigned int* qb =
        (const unsigned int*)(qp + ((size_t)b * C_ + h * CH_) * HW_);
    const unsigned int* kb =
        (const unsigned int*)(kp + ((size_t)b * C_ + h * CH_) * HW_);

    f32x4 acc[3][3];
#pragma unroll
    for (int mi = 0; mi < 3; ++mi)
#pragma unroll
        for (int ni = 0; ni < 3; ++ni) acc[mi][ni] = (f32x4)(0.f);

    for (int s = 0; s < 2; ++s) {
        int base2 = (chunk * 256 + s * 128) >> 1;
        __syncthreads();
#pragma unroll
        for (int i = 0; i < 12; ++i) {
            int p = t + i * 256;
            int c = p >> 6, jp = p & 63;
            int da = c * 66 + jp;
            ((unsigned int*)qh)[da] = qb[(size_t)c * (HW_ / 2) + base2 + jp];
            ((unsigned int*)kh)[da] = kb[(size_t)c * (HW_ / 2) + base2 + jp];
        }
        __syncthreads();
        bf16x8 fqh[3], fkh[3];
#pragma unroll
        for (int mi = 0; mi < 3; ++mi) {
            int off = (lm + 16 * mi) * 132 + w * 32 + kg * 8;
            fqh[mi] = __builtin_bit_cast(bf16x8, *(const u16x8*)&qh[off]);
            fkh[mi] = __builtin_bit_cast(bf16x8, *(const u16x8*)&kh[off]);
        }
#pragma unroll
        for (int mi = 0; mi < 3; ++mi)
#pragma unroll
            for (int ni = 0; ni < 3; ++ni)
                acc[mi][ni] = __builtin_amdgcn_mfma_f32_16x16x32_bf16(
                    fqh[mi], fkh[ni], acc[mi][ni], 0, 0, 0);
    }
    __syncthreads();
#pragma unroll
    for (int mi = 0; mi < 3; ++mi)
#pragma unroll
        for (int ni = 0; ni < 3; ++ni) {
            int tile = mi * 3 + ni;
            *(f32x4*)&red[w * 2304 + tile * 256 + lane * 4] = acc[mi][ni];
        }
    __syncthreads();
    size_t ob = ((size_t)(b * HEADS_ + h) * CHUNKS_ + chunk) * 2304;
    for (int idx = t; idx < 2304; idx += 256) {
        float sv = (red[idx] + red[2304 + idx]) +
                   (red[4608 + idx] + red[6912 + idx]);
        int tile = idx >> 8, li = idx & 255;
        int ln = li >> 2, r = li & 3;
        int mi = tile / 3, ni = tile - mi * 3;
        int sidx = (mi * 16 + (ln >> 4) * 4 + r) * 48 + ni * 16 + (ln & 15);
        Sp[ob + sidx] = sv;
    }
}

// per-(bh, q-row c): reduce chunk partials, norms+temp scale, wave softmax,
// write P[bh][d*48+c]
__global__ __launch_bounds__(256, 4) void k4r_softmax(
    const float* __restrict__ Sp, const float* __restrict__ ssPq,
    const float* __restrict__ ssPk, const float* __restrict__ temp,
    float* __restrict__ P) {
    __shared__ float red[4][64];
    int t = threadIdx.x;
    int w = t >> 6, d = t & 63;
    int c = blockIdx.x, bh = blockIdx.y;
    int b = bh >> 2, h = bh & 3;
    float s = 0.f;
    if (d < 48) {
        const float* sp = Sp + (size_t)bh * CHUNKS_ * 2304 + c * 48 + d;
#pragma unroll
        for (int j = 0; j < 16; ++j)
            s += sp[(size_t)(w * 16 + j) * 2304];
    }
    red[w][d] = s;
    __syncthreads();
    if (w == 0) {
        float tot = (red[0][d] + red[1][d]) + (red[2][d] + red[3][d]);
        const float* spq = ssPq + ((size_t)b * C_ + h * CH_ + c) * 4;
        float rq = 1.f / fmaxf(
            sqrtf(fmaxf((spq[0] + spq[1]) + (spq[2] + spq[3]), 0.f)), 1e-12f);
        float logit = -1e30f;
        if (d < 48) {
            const float* spk = ssPk + ((size_t)b * C_ + h * CH_ + d) * 4;
            float rk = 1.f / fmaxf(
                sqrtf(fmaxf((spk[0] + spk[1]) + (spk[2] + spk[3]), 0.f)), 1e-12f);
            logit = tot * (rq * temp[h]) * rk;
        }
        float m = logit;
#pragma unroll
        for (int mm = 1; mm < 64; mm <<= 1) m = fmaxf(m, __shfl_xor(m, mm, 64));
        float e = (d < 48) ? expf(logit - m) : 0.f;
        float sum = e;
#pragma unroll
        for (int mm = 1; mm < 64; mm <<= 1) sum += __shfl_xor(sum, mm, 64);
        if (d < 48)
            P[(size_t)bh * 2304 + d * 48 + c] = e * (1.f / sum);
    }
}

// MT fold: MT[b][o][h*48+d] = sum_c wp[o][h*48+c] * P[b,h][d][c], bf16 out.
__global__ __launch_bounds__(256, 2) void k4c_fold(
    const float* __restrict__ P, const float* __restrict__ wp,
    unsigned short* __restrict__ MTb) {
    __shared__ float sP[4 * 48 * 49];   // [h][d][c] stride 49
    __shared__ float wpL[16 * 192];     // [o_local][cg]
    int t = threadIdx.x;
    int o0 = blockIdx.x * 16, b = blockIdx.y;
    const float* Pb = P + (size_t)b * 4 * 2304;
    for (int i = t; i < 4 * 2304; i += 256) {
        int h = i / 2304, rem = i - h * 2304;
        int d = rem / 48, cc = rem - d * 48;
        sP[h * 2352 + d * 49 + cc] = Pb[i];
    }
    for (int i = t; i < 16 * 192; i += 256) {
        int o = i / 192, cc = i - o * 192;
        wpL[i] = wp[(size_t)(o0 + o) * C_ + cc];
    }
    __syncthreads();
    for (int i = t; i < 16 * 192; i += 256) {
        int o = i / 192, cg = i - o * 192;
        int h = cg / 48, d = cg - h * 48;
        const float* wrow = &wpL[o * 192 + h * 48];
        const float* prow = &sP[h * 2352 + d * 49];
        float sum = 0.f;
#pragma unroll
        for (int c = 0; c < 48; ++c) sum = fmaf(wrow[c], prow[c], sum);
        MTb[((size_t)b * C_ + o0 + o) * C_ + cg] = rne_bf16(sum);
    }
}

extern "C" void kernel_launch(void* const* d_in, const int* in_sizes, int n_in,
                              void* d_out, int out_size, void* d_ws, size_t ws_size,
                              hipStream_t stream) {
    const float* x     = (const float*)d_in[0];
    const float* wqkv  = (const float*)d_in[1];
    const float* wdw   = (const float*)d_in[2];
    const float* wproj = (const float*)d_in[3];
    const float* temp  = (const float*)d_in[4];
    float* out = (float*)d_out;
    char* ws = (char*)d_ws;

    unsigned short* wqkvB = (unsigned short*)(ws + 0);          // 221184 B
    unsigned short* MTb   = (unsigned short*)(ws + 221184);     // 147456 B
    float* P    = (float*)(ws + 368640);                        // 147456 B
    float* ssPq = (float*)(ws + 516096);                        // 12288 B
    float* ssPk = (float*)(ws + 528384);                        // 12288 B
    float* y1 = (float*)(ws + 540672);                          // 50331648 B
    float* Sp = y1;                                             // aliases y1
    unsigned short* q = (unsigned short*)(ws + 50872320);       // 25165824 B
    unsigned short* k = (unsigned short*)(ws + 76038144);       // 25165824 B
    unsigned short* v = q;                                      // v reuses q slab

    hipLaunchKernelGGL(k0_bf16, dim3(432), dim3(256), 0, stream,
                       wqkv, wqkvB, 576 * 192);
    // q
    hipLaunchKernelGGL(kg_f32, dim3(64, 3, 4), dim3(256), 0, stream,
                       wqkvB, 0, x, y1);
    hipLaunchKernelGGL(k2_dwconv, dim3(4, 192, 4), dim3(256), 0, stream,
                       y1, wdw, q, ssPq, 0);
    // k
    hipLaunchKernelGGL(kg_f32, dim3(64, 3, 4), dim3(256), 0, stream,
                       wqkvB + 192 * 192, 0, x, y1);
    hipLaunchKernelGGL(k2_dwconv, dim3(4, 192, 4), dim3(256), 0, stream,
                       y1, wdw, k, ssPk, 1);
    // attention -> P -> MT (bf16)
    hipLaunchKernelGGL(k3_qk, dim3(CHUNKS_, 4, 4), dim3(256), 0, stream, q, k, Sp);
    hipLaunchKernelGGL(k4r_softmax, dim3(48, 16), dim3(256), 0, stream,
                       Sp, ssPq, ssPk, temp, P);
    hipLaunchKernelGGL(k4c_fold, dim3(12, 4), dim3(256), 0, stream,
                       P, wproj, MTb);
    // v (bf16, into q slab)
    hipLaunchKernelGGL(kg_f32, dim3(64, 3, 4), dim3(256), 0, stream,
                       wqkvB + 2 * 192 * 192, 0, x, y1);
    hipLaunchKernelGGL(k2_dwconv, dim3(4, 192, 4), dim3(256), 0, stream,
                       y1, wdw, v, (float*)nullptr, 2);
    // out = M @ v
    hipLaunchKernelGGL(kg_b16, dim3(64, 3, 4), dim3(256), 0, stream,
                       MTb, C_ * C_, v, out);
}

// Round 17
// 150.417 us; speedup vs baseline: 1.8372x; 1.0822x over previous
//
#include <hip/hip_runtime.h>
#include <hip/hip_bf16.h>
#include <math.h>

// Restormer-style channel attention. Round 17: y1 intermediate -> bf16.
// kg_f32 emits bf16 y1 (write 49->24.6MB); k2 reads u16 (fetch halves).
// dwconv math stays f32. Everything else frozen from R16 (162.8us).
// B=4, C=192, H=W=128, HEADS=4, ch=48, HW=16384.

#define B_ 4
#define C_ 192
#define H_ 128
#define W_ 128
#define HW_ 16384
#define HEADS_ 4
#define CH_ 48
#define CHUNKS_ 64

typedef __attribute__((ext_vector_type(8))) __bf16 bf16x8;
typedef __attribute__((ext_vector_type(8))) unsigned short u16x8;
typedef __attribute__((ext_vector_type(4))) float f32x4;

__device__ __forceinline__ unsigned short rne_bf16(float f) {
    unsigned int u = __float_as_uint(f);
    u += 0x7FFFu + ((u >> 16) & 1u);
    return (unsigned short)(u >> 16);
}
__device__ __forceinline__ float bf16_f32(unsigned short h) {
    return __uint_as_float(((unsigned int)h) << 16);
}

// weights -> bf16 (RNE)
__global__ void k0_bf16(const float* __restrict__ wq,
                        unsigned short* __restrict__ wB, int n) {
    int idx = blockIdx.x * 256 + threadIdx.x;
    if (idx < n) wB[idx] = rne_bf16(wq[idx]);
}

// ---- GEMM: Y_bf16[b][m][p] = sum_k A_bf16[m][k] * rne(X[b][k][p]) ----
// Block 64m x 256px, 4 waves. Double-buffered LDS, 1 barrier/stage,
// next-tile loads issued before the MFMA phase. Output bf16 u16.
__global__ __launch_bounds__(256, 3) void kg_f32(
    const unsigned short* __restrict__ A, int aStrideB,
    const float* __restrict__ X, unsigned short* __restrict__ Y) {
    __shared__ unsigned short AL[2][64 * 40];
    __shared__ unsigned short BL[2][256 * 40];
    int t = threadIdx.x;
    int wave = t >> 6, lane = t & 63;
    int lm = lane & 15, kg = lane >> 4;
    int p0 = blockIdx.x * 256;
    int m0 = blockIdx.y * 64;
    int b = blockIdx.z;
    const unsigned short* Ab = A + (size_t)b * aStrideB + (size_t)m0 * C_;
    const float* Xb = X + (size_t)b * C_ * HW_ + p0 + t;
    int ar = t >> 2, ac = (t & 3) * 8;
    size_t arow = (size_t)ar * C_ + ac;

    f32x4 acc[4][4];
#pragma unroll
    for (int mi = 0; mi < 4; ++mi)
#pragma unroll
        for (int ni = 0; ni < 4; ++ni) acc[mi][ni] = (f32x4)(0.f);

    float xv[32];
    u16x8 av;
#pragma unroll
    for (int i = 0; i < 32; ++i) xv[i] = Xb[(size_t)i * HW_];
    av = *(const u16x8*)&Ab[arow];
    *(u16x8*)&AL[0][ar * 40 + ac] = av;
#pragma unroll
    for (int c8 = 0; c8 < 4; ++c8) {
        u16x8 hh;
#pragma unroll
        for (int j = 0; j < 8; ++j) hh[j] = rne_bf16(xv[c8 * 8 + j]);
        *(u16x8*)&BL[0][t * 40 + c8 * 8] = hh;
    }
    __syncthreads();

    for (int s = 0; s < 6; ++s) {
        int cur = s & 1;
        if (s < 5) {
            int kn = (s + 1) * 32;
            const float* xp = Xb + (size_t)kn * HW_;
#pragma unroll
            for (int i = 0; i < 32; ++i) xv[i] = xp[(size_t)i * HW_];
            av = *(const u16x8*)&Ab[arow + kn];
        }
        bf16x8 fah[4], fbh[4];
#pragma unroll
        for (int mi = 0; mi < 4; ++mi) {
            int ro = (lm + mi * 16) * 40 + kg * 8;
            fah[mi] = __builtin_bit_cast(bf16x8, *(const u16x8*)&AL[cur][ro]);
        }
#pragma unroll
        for (int ni = 0; ni < 4; ++ni) {
            int ro = (wave * 64 + ni * 16 + lm) * 40 + kg * 8;
            fbh[ni] = __builtin_bit_cast(bf16x8, *(const u16x8*)&BL[cur][ro]);
        }
#pragma unroll
        for (int mi = 0; mi < 4; ++mi)
#pragma unroll
            for (int ni = 0; ni < 4; ++ni)
                acc[mi][ni] = __builtin_amdgcn_mfma_f32_16x16x32_bf16(
                    fah[mi], fbh[ni], acc[mi][ni], 0, 0, 0);
        if (s < 5) {
            int nxt = cur ^ 1;
            *(u16x8*)&AL[nxt][ar * 40 + ac] = av;
#pragma unroll
            for (int c8 = 0; c8 < 4; ++c8) {
                u16x8 hh;
#pragma unroll
                for (int j = 0; j < 8; ++j) hh[j] = rne_bf16(xv[c8 * 8 + j]);
                *(u16x8*)&BL[nxt][t * 40 + c8 * 8] = hh;
            }
        }
        __syncthreads();
    }
#pragma unroll
    for (int mi = 0; mi < 4; ++mi)
#pragma unroll
        for (int ni = 0; ni < 4; ++ni) {
            int oc = m0 + mi * 16 + kg * 4;
            int px = p0 + wave * 64 + ni * 16 + lm;
            unsigned short* yp = Y + ((size_t)b * C_ + oc) * HW_ + px;
#pragma unroll
            for (int r = 0; r < 4; ++r)
                yp[(size_t)r * HW_] = rne_bf16(acc[mi][ni][r]);
        }
}

// bf16-input variant: X is u16 bf16 (the v slab); output f32 (d_out)
__global__ __launch_bounds__(256, 3) void kg_b16(
    const unsigned short* __restrict__ A, int aStrideB,
    const unsigned short* __restrict__ X, float* __restrict__ Y) {
    __shared__ unsigned short AL[2][64 * 40];
    __shared__ unsigned short BL[2][256 * 40];
    int t = threadIdx.x;
    int wave = t >> 6, lane = t & 63;
    int lm = lane & 15, kg = lane >> 4;
    int p0 = blockIdx.x * 256;
    int m0 = blockIdx.y * 64;
    int b = blockIdx.z;
    const unsigned short* Ab = A + (size_t)b * aStrideB + (size_t)m0 * C_;
    const unsigned short* Xb = X + (size_t)b * C_ * HW_ + p0 + t;
    int ar = t >> 2, ac = (t & 3) * 8;
    size_t arow = (size_t)ar * C_ + ac;

    f32x4 acc[4][4];
#pragma unroll
    for (int mi = 0; mi < 4; ++mi)
#pragma unroll
        for (int ni = 0; ni < 4; ++ni) acc[mi][ni] = (f32x4)(0.f);

    unsigned short xv[32];
    u16x8 av;
#pragma unroll
    for (int i = 0; i < 32; ++i) xv[i] = Xb[(size_t)i * HW_];
    av = *(const u16x8*)&Ab[arow];
    *(u16x8*)&AL[0][ar * 40 + ac] = av;
#pragma unroll
    for (int c8 = 0; c8 < 4; ++c8) {
        u16x8 hh;
#pragma unroll
        for (int j = 0; j < 8; ++j) hh[j] = xv[c8 * 8 + j];
        *(u16x8*)&BL[0][t * 40 + c8 * 8] = hh;
    }
    __syncthreads();

    for (int s = 0; s < 6; ++s) {
        int cur = s & 1;
        if (s < 5) {
            int kn = (s + 1) * 32;
            const unsigned short* xp = Xb + (size_t)kn * HW_;
#pragma unroll
            for (int i = 0; i < 32; ++i) xv[i] = xp[(size_t)i * HW_];
            av = *(const u16x8*)&Ab[arow + kn];
        }
        bf16x8 fah[4], fbh[4];
#pragma unroll
        for (int mi = 0; mi < 4; ++mi) {
            int ro = (lm + mi * 16) * 40 + kg * 8;
            fah[mi] = __builtin_bit_cast(bf16x8, *(const u16x8*)&AL[cur][ro]);
        }
#pragma unroll
        for (int ni = 0; ni < 4; ++ni) {
            int ro = (wave * 64 + ni * 16 + lm) * 40 + kg * 8;
            fbh[ni] = __builtin_bit_cast(bf16x8, *(const u16x8*)&BL[cur][ro]);
        }
#pragma unroll
        for (int mi = 0; mi < 4; ++mi)
#pragma unroll
            for (int ni = 0; ni < 4; ++ni)
                acc[mi][ni] = __builtin_amdgcn_mfma_f32_16x16x32_bf16(
                    fah[mi], fbh[ni], acc[mi][ni], 0, 0, 0);
        if (s < 5) {
            int nxt = cur ^ 1;
            *(u16x8*)&AL[nxt][ar * 40 + ac] = av;
#pragma unroll
            for (int c8 = 0; c8 < 4; ++c8) {
                u16x8 hh;
#pragma unroll
                for (int j = 0; j < 8; ++j) hh[j] = xv[c8 * 8 + j];
                *(u16x8*)&BL[nxt][t * 40 + c8 * 8] = hh;
            }
        }
        __syncthreads();
    }
#pragma unroll
    for (int mi = 0; mi < 4; ++mi)
#pragma unroll
        for (int ni = 0; ni < 4; ++ni) {
            int oc = m0 + mi * 16 + kg * 4;
            int px = p0 + wave * 64 + ni * 16 + lm;
            float* yp = Y + ((size_t)b * C_ + oc) * HW_ + px;
#pragma unroll
            for (int r = 0; r < 4; ++r) yp[(size_t)r * HW_] = acc[mi][ni][r];
        }
}

// depthwise 3x3 on bf16 y1 (f32 math), zero pad; 4x4 register tile.
// Emits bf16 u16. If ssP != nullptr, per-block sum-of-squares of the
// ROUNDED outputs.
__global__ __launch_bounds__(256, 6) void k2_dwconv(
    const unsigned short* __restrict__ y1, const float* __restrict__ wdw,
    unsigned short* __restrict__ dst, float* __restrict__ ssP, int g) {
    __shared__ float wss[4];
    int t = threadIdx.x;
    int c = blockIdx.y, b = blockIdx.z;
    int cg = (t & 31) * 4;
    int r0i = blockIdx.x * 32 + (t >> 5) * 4;
    const unsigned short* yp = y1 + ((size_t)b * C_ + c) * HW_;
    const float* wd = wdw + (size_t)(g * C_ + c) * 9;
    float w0 = wd[0], w1 = wd[1], w2 = wd[2];
    float w3 = wd[3], w4 = wd[4], w5 = wd[5];
    float w6 = wd[6], w7 = wd[7], w8 = wd[8];
    bool lv = cg > 0, rv = cg < W_ - 4;

    float4 mid[6];
    float lf[6], rt[6];
#pragma unroll
    for (int i = 0; i < 6; ++i) {
        int rr = r0i - 1 + i;
        if (rr >= 0 && rr < H_) {
            const unsigned short* rowp = yp + (size_t)rr * W_;
            ushort4 mv = *(const ushort4*)&rowp[cg];
            mid[i] = make_float4(bf16_f32(mv.x), bf16_f32(mv.y),
                                 bf16_f32(mv.z), bf16_f32(mv.w));
            lf[i] = lv ? bf16_f32(rowp[cg - 1]) : 0.f;
            rt[i] = rv ? bf16_f32(rowp[cg + 4]) : 0.f;
        } else {
            mid[i] = make_float4(0.f, 0.f, 0.f, 0.f);
            lf[i] = 0.f;
            rt[i] = 0.f;
        }
    }
    float ss = 0.f;
#pragma unroll
    for (int i = 0; i < 4; ++i) {
        float o0 = 0.f, o1 = 0.f, o2 = 0.f, o3 = 0.f;
#pragma unroll
        for (int k = 0; k < 3; ++k) {
            float4 m = mid[i + k];
            float L = lf[i + k], R = rt[i + k];
            float wa = (k == 0) ? w0 : (k == 1) ? w3 : w6;
            float wb = (k == 0) ? w1 : (k == 1) ? w4 : w7;
            float wc = (k == 0) ? w2 : (k == 1) ? w5 : w8;
            o0 = fmaf(wa, L,   fmaf(wb, m.x, fmaf(wc, m.y, o0)));
            o1 = fmaf(wa, m.x, fmaf(wb, m.y, fmaf(wc, m.z, o1)));
            o2 = fmaf(wa, m.y, fmaf(wb, m.z, fmaf(wc, m.w, o2)));
            o3 = fmaf(wa, m.z, fmaf(wb, m.w, fmaf(wc, R,   o3)));
        }
        unsigned short h0 = rne_bf16(o0), h1 = rne_bf16(o1);
        unsigned short h2 = rne_bf16(o2), h3 = rne_bf16(o3);
        float f0 = bf16_f32(h0), f1 = bf16_f32(h1);
        float f2 = bf16_f32(h2), f3 = bf16_f32(h3);
        ss += f0 * f0 + f1 * f1 + f2 * f2 + f3 * f3;
        size_t oi = ((size_t)b * C_ + c) * HW_ + (size_t)(r0i + i) * W_ + cg;
        ushort4 pk;
        pk.x = h0; pk.y = h1; pk.z = h2; pk.w = h3;
        *(ushort4*)&dst[oi] = pk;
    }
    if (ssP != nullptr) {
#pragma unroll
        for (int m = 32; m >= 1; m >>= 1) ss += __shfl_xor(ss, m, 64);
        if ((t & 63) == 0) wss[t >> 6] = ss;
        __syncthreads();
        if (t == 0)
            ssP[((size_t)b * C_ + c) * 4 + blockIdx.x] =
                (wss[0] + wss[1]) + (wss[2] + wss[3]);
    }
}

// S-GEMM partials, bf16 inputs. Per (b,h,chunk of 256 px): Sp[bh][chunk][2304]
__global__ __launch_bounds__(256, 4) void k3_qk(
    const unsigned short* __restrict__ qp, const unsigned short* __restrict__ kp,
    float* __restrict__ Sp) {
    __shared__ unsigned int smem[9216];
    unsigned short* qh = (unsigned short*)smem;   // [48][132] u16
    unsigned short* kh = qh + 6336;
    float* red = (float*)smem;                    // alias for reduce
    int t = threadIdx.x;
    int w = t >> 6, lane = t & 63, lm = lane & 15, kg = lane >> 4;
    int chunk = blockIdx.x, h = blockIdx.y, b = blockIdx.z;
    const unsigned int* qb =
        (const unsigned int*)(qp + ((size_t)b * C_ + h * CH_) * HW_);
    const unsigned int* kb =
        (const unsigned int*)(kp + ((size_t)b * C_ + h * CH_) * HW_);

    f32x4 acc[3][3];
#pragma unroll
    for (int mi = 0; mi < 3; ++mi)
#pragma unroll
        for (int ni = 0; ni < 3; ++ni) acc[mi][ni] = (f32x4)(0.f);

    for (int s = 0; s < 2; ++s) {
        int base2 = (chunk * 256 + s * 128) >> 1;
        __syncthreads();
#pragma unroll
        for (int i = 0; i < 12; ++i) {
            int p = t + i * 256;
            int c = p >> 6, jp = p & 63;
            int da = c * 66 + jp;
            ((unsigned int*)qh)[da] = qb[(size_t)c * (HW_ / 2) + base2 + jp];
            ((unsigned int*)kh)[da] = kb[(size_t)c * (HW_ / 2) + base2 + jp];
        }
        __syncthreads();
        bf16x8 fqh[3], fkh[3];
#pragma unroll
        for (int mi = 0; mi < 3; ++mi) {
            int off = (lm + 16 * mi) * 132 + w * 32 + kg * 8;
            fqh[mi] = __builtin_bit_cast(bf16x8, *(const u16x8*)&qh[off]);
            fkh[mi] = __builtin_bit_cast(bf16x8, *(const u16x8*)&kh[off]);
        }
#pragma unroll
        for (int mi = 0; mi < 3; ++mi)
#pragma unroll
            for (int ni = 0; ni < 3; ++ni)
                acc[mi][ni] = __builtin_amdgcn_mfma_f32_16x16x32_bf16(
                    fqh[mi], fkh[ni], acc[mi][ni], 0, 0, 0);
    }
    __syncthreads();
#pragma unroll
    for (int mi = 0; mi < 3; ++mi)
#pragma unroll
        for (int ni = 0; ni < 3; ++ni) {
            int tile = mi * 3 + ni;
            *(f32x4*)&red[w * 2304 + tile * 256 + lane * 4] = acc[mi][ni];
        }
    __syncthreads();
    size_t ob = ((size_t)(b * HEADS_ + h) * CHUNKS_ + chunk) * 2304;
    for (int idx = t; idx < 2304; idx += 256) {
        float sv = (red[idx] + red[2304 + idx]) +
                   (red[4608 + idx] + red[6912 + idx]);
        int tile = idx >> 8, li = idx & 255;
        int ln = li >> 2, r = li & 3;
        int mi = tile / 3, ni = tile - mi * 3;
        int sidx = (mi * 16 + (ln >> 4) * 4 + r) * 48 + ni * 16 + (ln & 15);
        Sp[ob + sidx] = sv;
    }
}

// per-(bh, q-row c): reduce chunk partials, norms+temp scale, wave softmax,
// write P[bh][d*48+c]
__global__ __launch_bounds__(256, 4) void k4r_softmax(
    const float* __restrict__ Sp, const float* __restrict__ ssPq,
    const float* __restrict__ ssPk, const float* __restrict__ temp,
    float* __restrict__ P) {
    __shared__ float red[4][64];
    int t = threadIdx.x;
    int w = t >> 6, d = t & 63;
    int c = blockIdx.x, bh = blockIdx.y;
    int b = bh >> 2, h = bh & 3;
    float s = 0.f;
    if (d < 48) {
        const float* sp = Sp + (size_t)bh * CHUNKS_ * 2304 + c * 48 + d;
#pragma unroll
        for (int j = 0; j < 16; ++j)
            s += sp[(size_t)(w * 16 + j) * 2304];
    }
    red[w][d] = s;
    __syncthreads();
    if (w == 0) {
        float tot = (red[0][d] + red[1][d]) + (red[2][d] + red[3][d]);
        const float* spq = ssPq + ((size_t)b * C_ + h * CH_ + c) * 4;
        float rq = 1.f / fmaxf(
            sqrtf(fmaxf((spq[0] + spq[1]) + (spq[2] + spq[3]), 0.f)), 1e-12f);
        float logit = -1e30f;
        if (d < 48) {
            const float* spk = ssPk + ((size_t)b * C_ + h * CH_ + d) * 4;
            float rk = 1.f / fmaxf(
                sqrtf(fmaxf((spk[0] + spk[1]) + (spk[2] + spk[3]), 0.f)), 1e-12f);
            logit = tot * (rq * temp[h]) * rk;
        }
        float m = logit;
#pragma unroll
        for (int mm = 1; mm < 64; mm <<= 1) m = fmaxf(m, __shfl_xor(m, mm, 64));
        float e = (d < 48) ? expf(logit - m) : 0.f;
        float sum = e;
#pragma unroll
        for (int mm = 1; mm < 64; mm <<= 1) sum += __shfl_xor(sum, mm, 64);
        if (d < 48)
            P[(size_t)bh * 2304 + d * 48 + c] = e * (1.f / sum);
    }
}

// MT fold: MT[b][o][h*48+d] = sum_c wp[o][h*48+c] * P[b,h][d][c], bf16 out.
__global__ __launch_bounds__(256, 2) void k4c_fold(
    const float* __restrict__ P, const float* __restrict__ wp,
    unsigned short* __restrict__ MTb) {
    __shared__ float sP[4 * 48 * 49];   // [h][d][c] stride 49
    __shared__ float wpL[16 * 192];     // [o_local][cg]
    int t = threadIdx.x;
    int o0 = blockIdx.x * 16, b = blockIdx.y;
    const float* Pb = P + (size_t)b * 4 * 2304;
    for (int i = t; i < 4 * 2304; i += 256) {
        int h = i / 2304, rem = i - h * 2304;
        int d = rem / 48, cc = rem - d * 48;
        sP[h * 2352 + d * 49 + cc] = Pb[i];
    }
    for (int i = t; i < 16 * 192; i += 256) {
        int o = i / 192, cc = i - o * 192;
        wpL[i] = wp[(size_t)(o0 + o) * C_ + cc];
    }
    __syncthreads();
    for (int i = t; i < 16 * 192; i += 256) {
        int o = i / 192, cg = i - o * 192;
        int h = cg / 48, d = cg - h * 48;
        const float* wrow = &wpL[o * 192 + h * 48];
        const float* prow = &sP[h * 2352 + d * 49];
        float sum = 0.f;
#pragma unroll
        for (int c = 0; c < 48; ++c) sum = fmaf(wrow[c], prow[c], sum);
        MTb[((size_t)b * C_ + o0 + o) * C_ + cg] = rne_bf16(sum);
    }
}

extern "C" void kernel_launch(void* const* d_in, const int* in_sizes, int n_in,
                              void* d_out, int out_size, void* d_ws, size_t ws_size,
                              hipStream_t stream) {
    const float* x     = (const float*)d_in[0];
    const float* wqkv  = (const float*)d_in[1];
    const float* wdw   = (const float*)d_in[2];
    const float* wproj = (const float*)d_in[3];
    const float* temp  = (const float*)d_in[4];
    float* out = (float*)d_out;
    char* ws = (char*)d_ws;

    unsigned short* wqkvB = (unsigned short*)(ws + 0);          // 221184 B
    unsigned short* MTb   = (unsigned short*)(ws + 221184);     // 147456 B
    float* P    = (float*)(ws + 368640);                        // 147456 B
    float* ssPq = (float*)(ws + 516096);                        // 12288 B
    float* ssPk = (float*)(ws + 528384);                        // 12288 B
    unsigned short* y1 = (unsigned short*)(ws + 540672);        // 25165824 B
    float* Sp = (float*)(ws + 540672);                          // aliases y1
    unsigned short* q = (unsigned short*)(ws + 25706496);       // 25165824 B
    unsigned short* k = (unsigned short*)(ws + 50872320);       // 25165824 B
    unsigned short* v = q;                                      // v reuses q slab

    hipLaunchKernelGGL(k0_bf16, dim3(432), dim3(256), 0, stream,
                       wqkv, wqkvB, 576 * 192);
    // q
    hipLaunchKernelGGL(kg_f32, dim3(64, 3, 4), dim3(256), 0, stream,
                       wqkvB, 0, x, y1);
    hipLaunchKernelGGL(k2_dwconv, dim3(4, 192, 4), dim3(256), 0, stream,
                       y1, wdw, q, ssPq, 0);
    // k
    hipLaunchKernelGGL(kg_f32, dim3(64, 3, 4), dim3(256), 0, stream,
                       wqkvB + 192 * 192, 0, x, y1);
    hipLaunchKernelGGL(k2_dwconv, dim3(4, 192, 4), dim3(256), 0, stream,
                       y1, wdw, k, ssPk, 1);
    // attention -> P -> MT (bf16)
    hipLaunchKernelGGL(k3_qk, dim3(CHUNKS_, 4, 4), dim3(256), 0, stream, q, k, Sp);
    hipLaunchKernelGGL(k4r_softmax, dim3(48, 16), dim3(256), 0, stream,
                       Sp, ssPq, ssPk, temp, P);
    hipLaunchKernelGGL(k4c_fold, dim3(12, 4), dim3(256), 0, stream,
                       P, wproj, MTb);
    // v (bf16, into q slab)
    hipLaunchKernelGGL(kg_f32, dim3(64, 3, 4), dim3(256), 0, stream,
                       wqkvB + 2 * 192 * 192, 0, x, y1);
    hipLaunchKernelGGL(k2_dwconv, dim3(4, 192, 4), dim3(256), 0, stream,
                       y1, wdw, v, (float*)nullptr, 2);
    // out = M @ v
    hipLaunchKernelGGL(kg_b16, dim3(64, 3, 4), dim3(256), 0, stream,
                       MTb, C_ * C_, v, out);
}

// Round 18
// 132.028 us; speedup vs baseline: 2.0931x; 1.1393x over previous
//
#include <hip/hip_runtime.h>
#include <hip/hip_bf16.h>
#include <math.h>

// Restormer-style channel attention. Round 18: launch fusion.
// - kg_qkv: ONE GEMM launch for all 576 qkv output channels (was 3).
// - k2_all: ONE dwconv launch over 576 channels (was 3); merged ssQK.
// - consumers use batch-stride 576 into the fused qkv slab.
// Arithmetic identical to R17 (absmax 9.77e-4). 10 -> 7 launches.
// B=4, C=192, H=W=128, HEADS=4, ch=48, HW=16384.

#define B_ 4
#define C_ 192
#define C3_ 576
#define H_ 128
#define W_ 128
#define HW_ 16384
#define HEADS_ 4
#define CH_ 48
#define CHUNKS_ 64

typedef __attribute__((ext_vector_type(8))) __bf16 bf16x8;
typedef __attribute__((ext_vector_type(8))) unsigned short u16x8;
typedef __attribute__((ext_vector_type(4))) float f32x4;

__device__ __forceinline__ unsigned short rne_bf16(float f) {
    unsigned int u = __float_as_uint(f);
    u += 0x7FFFu + ((u >> 16) & 1u);
    return (unsigned short)(u >> 16);
}
__device__ __forceinline__ float bf16_f32(unsigned short h) {
    return __uint_as_float(((unsigned int)h) << 16);
}

// weights -> bf16 (RNE)
__global__ void k0_bf16(const float* __restrict__ wq,
                        unsigned short* __restrict__ wB, int n) {
    int idx = blockIdx.x * 256 + threadIdx.x;
    if (idx < n) wB[idx] = rne_bf16(wq[idx]);
}

// ---- qkv GEMM: Y_bf16[b][m][p] = sum_k A_bf16[m][k]*rne(X[b][k][p]) ----
// m spans all 576 rows (grid y = 9). Double-buffered LDS, 1 barrier/stage,
// register prefetch before MFMA phase. Y batch stride = 576*HW (u16).
__global__ __launch_bounds__(256, 3) void kg_qkv(
    const unsigned short* __restrict__ A, const float* __restrict__ X,
    unsigned short* __restrict__ Y) {
    __shared__ unsigned short AL[2][64 * 40];
    __shared__ unsigned short BL[2][256 * 40];
    int t = threadIdx.x;
    int wave = t >> 6, lane = t & 63;
    int lm = lane & 15, kg = lane >> 4;
    int p0 = blockIdx.x * 256;
    int m0 = blockIdx.y * 64;
    int b = blockIdx.z;
    const unsigned short* Ab = A + (size_t)m0 * C_;
    const float* Xb = X + (size_t)b * C_ * HW_ + p0 + t;
    int ar = t >> 2, ac = (t & 3) * 8;
    size_t arow = (size_t)ar * C_ + ac;

    f32x4 acc[4][4];
#pragma unroll
    for (int mi = 0; mi < 4; ++mi)
#pragma unroll
        for (int ni = 0; ni < 4; ++ni) acc[mi][ni] = (f32x4)(0.f);

    float xv[32];
    u16x8 av;
#pragma unroll
    for (int i = 0; i < 32; ++i) xv[i] = Xb[(size_t)i * HW_];
    av = *(const u16x8*)&Ab[arow];
    *(u16x8*)&AL[0][ar * 40 + ac] = av;
#pragma unroll
    for (int c8 = 0; c8 < 4; ++c8) {
        u16x8 hh;
#pragma unroll
        for (int j = 0; j < 8; ++j) hh[j] = rne_bf16(xv[c8 * 8 + j]);
        *(u16x8*)&BL[0][t * 40 + c8 * 8] = hh;
    }
    __syncthreads();

    for (int s = 0; s < 6; ++s) {
        int cur = s & 1;
        if (s < 5) {
            int kn = (s + 1) * 32;
            const float* xp = Xb + (size_t)kn * HW_;
#pragma unroll
            for (int i = 0; i < 32; ++i) xv[i] = xp[(size_t)i * HW_];
            av = *(const u16x8*)&Ab[arow + kn];
        }
        bf16x8 fah[4], fbh[4];
#pragma unroll
        for (int mi = 0; mi < 4; ++mi) {
            int ro = (lm + mi * 16) * 40 + kg * 8;
            fah[mi] = __builtin_bit_cast(bf16x8, *(const u16x8*)&AL[cur][ro]);
        }
#pragma unroll
        for (int ni = 0; ni < 4; ++ni) {
            int ro = (wave * 64 + ni * 16 + lm) * 40 + kg * 8;
            fbh[ni] = __builtin_bit_cast(bf16x8, *(const u16x8*)&BL[cur][ro]);
        }
#pragma unroll
        for (int mi = 0; mi < 4; ++mi)
#pragma unroll
            for (int ni = 0; ni < 4; ++ni)
                acc[mi][ni] = __builtin_amdgcn_mfma_f32_16x16x32_bf16(
                    fah[mi], fbh[ni], acc[mi][ni], 0, 0, 0);
        if (s < 5) {
            int nxt = cur ^ 1;
            *(u16x8*)&AL[nxt][ar * 40 + ac] = av;
#pragma unroll
            for (int c8 = 0; c8 < 4; ++c8) {
                u16x8 hh;
#pragma unroll
                for (int j = 0; j < 8; ++j) hh[j] = rne_bf16(xv[c8 * 8 + j]);
                *(u16x8*)&BL[nxt][t * 40 + c8 * 8] = hh;
            }
        }
        __syncthreads();
    }
#pragma unroll
    for (int mi = 0; mi < 4; ++mi)
#pragma unroll
        for (int ni = 0; ni < 4; ++ni) {
            int oc = m0 + mi * 16 + kg * 4;
            int px = p0 + wave * 64 + ni * 16 + lm;
            unsigned short* yp = Y + ((size_t)b * C3_ + oc) * HW_ + px;
#pragma unroll
            for (int r = 0; r < 4; ++r)
                yp[(size_t)r * HW_] = rne_bf16(acc[mi][ni][r]);
        }
}

// out GEMM: out[b][m][p] = sum_k MTb[b][m][k] * v_bf16[b][k][p]; v batch
// stride 576*HW (v = qkv + 2*192*HW). f32 output.
__global__ __launch_bounds__(256, 3) void kg_b16(
    const unsigned short* __restrict__ A, const unsigned short* __restrict__ X,
    float* __restrict__ Y) {
    __shared__ unsigned short AL[2][64 * 40];
    __shared__ unsigned short BL[2][256 * 40];
    int t = threadIdx.x;
    int wave = t >> 6, lane = t & 63;
    int lm = lane & 15, kg = lane >> 4;
    int p0 = blockIdx.x * 256;
    int m0 = blockIdx.y * 64;
    int b = blockIdx.z;
    const unsigned short* Ab = A + (size_t)b * C_ * C_ + (size_t)m0 * C_;
    const unsigned short* Xb = X + (size_t)b * C3_ * HW_ + p0 + t;
    int ar = t >> 2, ac = (t & 3) * 8;
    size_t arow = (size_t)ar * C_ + ac;

    f32x4 acc[4][4];
#pragma unroll
    for (int mi = 0; mi < 4; ++mi)
#pragma unroll
        for (int ni = 0; ni < 4; ++ni) acc[mi][ni] = (f32x4)(0.f);

    unsigned short xv[32];
    u16x8 av;
#pragma unroll
    for (int i = 0; i < 32; ++i) xv[i] = Xb[(size_t)i * HW_];
    av = *(const u16x8*)&Ab[arow];
    *(u16x8*)&AL[0][ar * 40 + ac] = av;
#pragma unroll
    for (int c8 = 0; c8 < 4; ++c8) {
        u16x8 hh;
#pragma unroll
        for (int j = 0; j < 8; ++j) hh[j] = xv[c8 * 8 + j];
        *(u16x8*)&BL[0][t * 40 + c8 * 8] = hh;
    }
    __syncthreads();

    for (int s = 0; s < 6; ++s) {
        int cur = s & 1;
        if (s < 5) {
            int kn = (s + 1) * 32;
            const unsigned short* xp = Xb + (size_t)kn * HW_;
#pragma unroll
            for (int i = 0; i < 32; ++i) xv[i] = xp[(size_t)i * HW_];
            av = *(const u16x8*)&Ab[arow + kn];
        }
        bf16x8 fah[4], fbh[4];
#pragma unroll
        for (int mi = 0; mi < 4; ++mi) {
            int ro = (lm + mi * 16) * 40 + kg * 8;
            fah[mi] = __builtin_bit_cast(bf16x8, *(const u16x8*)&AL[cur][ro]);
        }
#pragma unroll
        for (int ni = 0; ni < 4; ++ni) {
            int ro = (wave * 64 + ni * 16 + lm) * 40 + kg * 8;
            fbh[ni] = __builtin_bit_cast(bf16x8, *(const u16x8*)&BL[cur][ro]);
        }
#pragma unroll
        for (int mi = 0; mi < 4; ++mi)
#pragma unroll
            for (int ni = 0; ni < 4; ++ni)
                acc[mi][ni] = __builtin_amdgcn_mfma_f32_16x16x32_bf16(
                    fah[mi], fbh[ni], acc[mi][ni], 0, 0, 0);
        if (s < 5) {
            int nxt = cur ^ 1;
            *(u16x8*)&AL[nxt][ar * 40 + ac] = av;
#pragma unroll
            for (int c8 = 0; c8 < 4; ++c8) {
                u16x8 hh;
#pragma unroll
                for (int j = 0; j < 8; ++j) hh[j] = xv[c8 * 8 + j];
                *(u16x8*)&BL[nxt][t * 40 + c8 * 8] = hh;
            }
        }
        __syncthreads();
    }
#pragma unroll
    for (int mi = 0; mi < 4; ++mi)
#pragma unroll
        for (int ni = 0; ni < 4; ++ni) {
            int oc = m0 + mi * 16 + kg * 4;
            int px = p0 + wave * 64 + ni * 16 + lm;
            float* yp = Y + ((size_t)b * C_ + oc) * HW_ + px;
#pragma unroll
            for (int r = 0; r < 4; ++r) yp[(size_t)r * HW_] = acc[mi][ni][r];
        }
}

// depthwise 3x3 over ALL 576 channels (g = gc/192 implicit in weight index).
// bf16 in/out, f32 math. ss partials only for q,k channels (gc < 384):
// ssQK[(b*384 + gc)*4 + rowblk], sum of squares of ROUNDED outputs.
__global__ __launch_bounds__(256, 6) void k2_all(
    const unsigned short* __restrict__ y1, const float* __restrict__ wdw,
    unsigned short* __restrict__ qkv, float* __restrict__ ssQK) {
    __shared__ float wss[4];
    int t = threadIdx.x;
    int gc = blockIdx.y, b = blockIdx.z;
    int cg = (t & 31) * 4;
    int r0i = blockIdx.x * 32 + (t >> 5) * 4;
    const unsigned short* yp = y1 + ((size_t)b * C3_ + gc) * HW_;
    const float* wd = wdw + (size_t)gc * 9;
    float w0 = wd[0], w1 = wd[1], w2 = wd[2];
    float w3 = wd[3], w4 = wd[4], w5 = wd[5];
    float w6 = wd[6], w7 = wd[7], w8 = wd[8];
    bool lv = cg > 0, rv = cg < W_ - 4;

    float4 mid[6];
    float lf[6], rt[6];
#pragma unroll
    for (int i = 0; i < 6; ++i) {
        int rr = r0i - 1 + i;
        if (rr >= 0 && rr < H_) {
            const unsigned short* rowp = yp + (size_t)rr * W_;
            ushort4 mv = *(const ushort4*)&rowp[cg];
            mid[i] = make_float4(bf16_f32(mv.x), bf16_f32(mv.y),
                                 bf16_f32(mv.z), bf16_f32(mv.w));
            lf[i] = lv ? bf16_f32(rowp[cg - 1]) : 0.f;
            rt[i] = rv ? bf16_f32(rowp[cg + 4]) : 0.f;
        } else {
            mid[i] = make_float4(0.f, 0.f, 0.f, 0.f);
            lf[i] = 0.f;
            rt[i] = 0.f;
        }
    }
    float ss = 0.f;
#pragma unroll
    for (int i = 0; i < 4; ++i) {
        float o0 = 0.f, o1 = 0.f, o2 = 0.f, o3 = 0.f;
#pragma unroll
        for (int k = 0; k < 3; ++k) {
            float4 m = mid[i + k];
            float L = lf[i + k], R = rt[i + k];
            float wa = (k == 0) ? w0 : (k == 1) ? w3 : w6;
            float wb = (k == 0) ? w1 : (k == 1) ? w4 : w7;
            float wc = (k == 0) ? w2 : (k == 1) ? w5 : w8;
            o0 = fmaf(wa, L,   fmaf(wb, m.x, fmaf(wc, m.y, o0)));
            o1 = fmaf(wa, m.x, fmaf(wb, m.y, fmaf(wc, m.z, o1)));
            o2 = fmaf(wa, m.y, fmaf(wb, m.z, fmaf(wc, m.w, o2)));
            o3 = fmaf(wa, m.z, fmaf(wb, m.w, fmaf(wc, R,   o3)));
        }
        unsigned short h0 = rne_bf16(o0), h1 = rne_bf16(o1);
        unsigned short h2 = rne_bf16(o2), h3 = rne_bf16(o3);
        float f0 = bf16_f32(h0), f1 = bf16_f32(h1);
        float f2 = bf16_f32(h2), f3 = bf16_f32(h3);
        ss += f0 * f0 + f1 * f1 + f2 * f2 + f3 * f3;
        size_t oi = ((size_t)b * C3_ + gc) * HW_ + (size_t)(r0i + i) * W_ + cg;
        ushort4 pk;
        pk.x = h0; pk.y = h1; pk.z = h2; pk.w = h3;
        *(ushort4*)&qkv[oi] = pk;
    }
    if (gc < 2 * C_) {
#pragma unroll
        for (int m = 32; m >= 1; m >>= 1) ss += __shfl_xor(ss, m, 64);
        if ((t & 63) == 0) wss[t >> 6] = ss;
        __syncthreads();
        if (t == 0)
            ssQK[((size_t)b * 2 * C_ + gc) * 4 + blockIdx.x] =
                (wss[0] + wss[1]) + (wss[2] + wss[3]);
    }
}

// S-GEMM partials, bf16 inputs from fused qkv (batch stride 576*HW).
__global__ __launch_bounds__(256, 4) void k3_qk(
    const unsigned short* __restrict__ qkv, float* __restrict__ Sp) {
    __shared__ unsigned int smem[9216];
    unsigned short* qh = (unsigned short*)smem;   // [48][132] u16
    unsigned short* kh = qh + 6336;
    float* red = (float*)smem;                    // alias for reduce
    int t = threadIdx.x;
    int w = t >> 6, lane = t & 63, lm = lane & 15, kg = lane >> 4;
    int chunk = blockIdx.x, h = blockIdx.y, b = blockIdx.z;
    const unsigned int* qb =
        (const unsigned int*)(qkv + ((size_t)b * C3_ + h * CH_) * HW_);
    const unsigned int* kb =
        (const unsigned int*)(qkv + ((size_t)b * C3_ + C_ + h * CH_) * HW_);

    f32x4 acc[3][3];
#pragma unroll
    for (int mi = 0; mi < 3; ++mi)
#pragma unroll
        for (int ni = 0; ni < 3; ++ni) acc[mi][ni] = (f32x4)(0.f);

    for (int s = 0; s < 2; ++s) {
        int base2 = (chunk * 256 + s * 128) >> 1;
        __syncthreads();
#pragma unroll
        for (int i = 0; i < 12; ++i) {
            int p = t + i * 256;
            int c = p >> 6, jp = p & 63;
            int da = c * 66 + jp;
            ((unsigned int*)qh)[da] = qb[(size_t)c * (HW_ / 2) + base2 + jp];
            ((unsigned int*)kh)[da] = kb[(size_t)c * (HW_ / 2) + base2 + jp];
        }
        __syncthreads();
        bf16x8 fqh[3], fkh[3];
#pragma unroll
        for (int mi = 0; mi < 3; ++mi) {
            int off = (lm + 16 * mi) * 132 + w * 32 + kg * 8;
            fqh[mi] = __builtin_bit_cast(bf16x8, *(const u16x8*)&qh[off]);
            fkh[mi] = __builtin_bit_cast(bf16x8, *(const u16x8*)&kh[off]);
        }
#pragma unroll
        for (int mi = 0; mi < 3; ++mi)
#pragma unroll
            for (int ni = 0; ni < 3; ++ni)
                acc[mi][ni] = __builtin_amdgcn_mfma_f32_16x16x32_bf16(
                    fqh[mi], fkh[ni], acc[mi][ni], 0, 0, 0);
    }
    __syncthreads();
#pragma unroll
    for (int mi = 0; mi < 3; ++mi)
#pragma unroll
        for (int ni = 0; ni < 3; ++ni) {
            int tile = mi * 3 + ni;
            *(f32x4*)&red[w * 2304 + tile * 256 + lane * 4] = acc[mi][ni];
        }
    __syncthreads();
    size_t ob = ((size_t)(b * HEADS_ + h) * CHUNKS_ + chunk) * 2304;
    for (int idx = t; idx < 2304; idx += 256) {
        float sv = (red[idx] + red[2304 + idx]) +
                   (red[4608 + idx] + red[6912 + idx]);
        int tile = idx >> 8, li = idx & 255;
        int ln = li >> 2, r = li & 3;
        int mi = tile / 3, ni = tile - mi * 3;
        int sidx = (mi * 16 + (ln >> 4) * 4 + r) * 48 + ni * 16 + (ln & 15);
        Sp[ob + sidx] = sv;
    }
}

// per-(bh, q-row c): reduce chunk partials, norms+temp scale, wave softmax,
// write P[bh][d*48+c]
__global__ __launch_bounds__(256, 4) void k4r_softmax(
    const float* __restrict__ Sp, const float* __restrict__ ssQK,
    const float* __restrict__ temp, float* __restrict__ P) {
    __shared__ float red[4][64];
    int t = threadIdx.x;
    int w = t >> 6, d = t & 63;
    int c = blockIdx.x, bh = blockIdx.y;
    int b = bh >> 2, h = bh & 3;
    float s = 0.f;
    if (d < 48) {
        const float* sp = Sp + (size_t)bh * CHUNKS_ * 2304 + c * 48 + d;
#pragma unroll
        for (int j = 0; j < 16; ++j)
            s += sp[(size_t)(w * 16 + j) * 2304];
    }
    red[w][d] = s;
    __syncthreads();
    if (w == 0) {
        float tot = (red[0][d] + red[1][d]) + (red[2][d] + red[3][d]);
        const float* spq = ssQK + ((size_t)b * 2 * C_ + h * CH_ + c) * 4;
        float rq = 1.f / fmaxf(
            sqrtf(fmaxf((spq[0] + spq[1]) + (spq[2] + spq[3]), 0.f)), 1e-12f);
        float logit = -1e30f;
        if (d < 48) {
            const float* spk =
                ssQK + ((size_t)b * 2 * C_ + C_ + h * CH_ + d) * 4;
            float rk = 1.f / fmaxf(
                sqrtf(fmaxf((spk[0] + spk[1]) + (spk[2] + spk[3]), 0.f)), 1e-12f);
            logit = tot * (rq * temp[h]) * rk;
        }
        float m = logit;
#pragma unroll
        for (int mm = 1; mm < 64; mm <<= 1) m = fmaxf(m, __shfl_xor(m, mm, 64));
        float e = (d < 48) ? expf(logit - m) : 0.f;
        float sum = e;
#pragma unroll
        for (int mm = 1; mm < 64; mm <<= 1) sum += __shfl_xor(sum, mm, 64);
        if (d < 48)
            P[(size_t)bh * 2304 + d * 48 + c] = e * (1.f / sum);
    }
}

// MT fold: MT[b][o][h*48+d] = sum_c wp[o][h*48+c] * P[b,h][d][c], bf16 out.
__global__ __launch_bounds__(256, 2) void k4c_fold(
    const float* __restrict__ P, const float* __restrict__ wp,
    unsigned short* __restrict__ MTb) {
    __shared__ float sP[4 * 48 * 49];   // [h][d][c] stride 49
    __shared__ float wpL[16 * 192];     // [o_local][cg]
    int t = threadIdx.x;
    int o0 = blockIdx.x * 16, b = blockIdx.y;
    const float* Pb = P + (size_t)b * 4 * 2304;
    for (int i = t; i < 4 * 2304; i += 256) {
        int h = i / 2304, rem = i - h * 2304;
        int d = rem / 48, cc = rem - d * 48;
        sP[h * 2352 + d * 49 + cc] = Pb[i];
    }
    for (int i = t; i < 16 * 192; i += 256) {
        int o = i / 192, cc = i - o * 192;
        wpL[i] = wp[(size_t)(o0 + o) * C_ + cc];
    }
    __syncthreads();
    for (int i = t; i < 16 * 192; i += 256) {
        int o = i / 192, cg = i - o * 192;
        int h = cg / 48, d = cg - h * 48;
        const float* wrow = &wpL[o * 192 + h * 48];
        const float* prow = &sP[h * 2352 + d * 49];
        float sum = 0.f;
#pragma unroll
        for (int c = 0; c < 48; ++c) sum = fmaf(wrow[c], prow[c], sum);
        MTb[((size_t)b * C_ + o0 + o) * C_ + cg] = rne_bf16(sum);
    }
}

extern "C" void kernel_launch(void* const* d_in, const int* in_sizes, int n_in,
                              void* d_out, int out_size, void* d_ws, size_t ws_size,
                              hipStream_t stream) {
    const float* x     = (const float*)d_in[0];
    const float* wqkv  = (const float*)d_in[1];
    const float* wdw   = (const float*)d_in[2];
    const float* wproj = (const float*)d_in[3];
    const float* temp  = (const float*)d_in[4];
    float* out = (float*)d_out;
    char* ws = (char*)d_ws;

    unsigned short* wqkvB = (unsigned short*)(ws + 0);          // 221184 B
    unsigned short* MTb   = (unsigned short*)(ws + 221184);     // 147456 B
    float* P    = (float*)(ws + 368640);                        // 147456 B
    float* ssQK = (float*)(ws + 516096);                        // 24576 B
    unsigned short* y1qkv = (unsigned short*)(ws + 540672);     // 75497472 B
    float* Sp = (float*)(ws + 540672);                          // aliases y1qkv
    unsigned short* qkv = (unsigned short*)(ws + 76038144);     // 75497472 B
    // total 151535616 B = 151.5 MB

    hipLaunchKernelGGL(k0_bf16, dim3(432), dim3(256), 0, stream,
                       wqkv, wqkvB, 576 * 192);
    // all qkv conv1x1 in one launch
    hipLaunchKernelGGL(kg_qkv, dim3(64, 9, 4), dim3(256), 0, stream,
                       wqkvB, x, y1qkv);
    // all dwconv in one launch (q,k,v + ss partials for q,k)
    hipLaunchKernelGGL(k2_all, dim3(4, 576, 4), dim3(256), 0, stream,
                       y1qkv, wdw, qkv, ssQK);
    // attention -> P -> MT (bf16)
    hipLaunchKernelGGL(k3_qk, dim3(CHUNKS_, 4, 4), dim3(256), 0, stream, qkv, Sp);
    hipLaunchKernelGGL(k4r_softmax, dim3(48, 16), dim3(256), 0, stream,
                       Sp, ssQK, temp, P);
    hipLaunchKernelGGL(k4c_fold, dim3(12, 4), dim3(256), 0, stream,
                       P, wproj, MTb);
    // out = M @ v  (v = qkv + 2*C_*HW_, batch stride 576*HW)
    hipLaunchKernelGGL(kg_b16, dim3(64, 3, 4), dim3(256), 0, stream,
                       MTb, qkv + (size_t)2 * C_ * HW_, out);
}